// Round 2
// baseline (2149.810 us; speedup 1.0000x reference)
//
#include <hip/hip_runtime.h>
#include <hip/hip_bf16.h>
#include <math.h>

// Problem constants
#define Bdim 64
#define Cdim 128
#define Ldim 1024
#define BC   (Bdim * Cdim)      // 8192 rows
#define CLn  (Cdim * Ldim)      // 131072 features
#define TOT  (Bdim * CLn)       // 8388608 elements per (B,C,L) tensor

typedef unsigned short ushort_t;
__device__ inline float bf2f(ushort_t u) {
    return __uint_as_float(((unsigned)u) << 16);
}

// ---------------------------------------------------------------------------
// BN: per-feature mean/var over batch axis -> fused scale/shift
// ---------------------------------------------------------------------------
__global__ __launch_bounds__(256) void bn_stats_kernel(
    const float* __restrict__ x, const float* __restrict__ bn_g,
    const float* __restrict__ bn_b, float* __restrict__ scale,
    float* __restrict__ shift)
{
    int f = blockIdx.x * 256 + threadIdx.x;   // f < CLn (grid exact)
    float sum = 0.f, sumsq = 0.f;
    for (int b = 0; b < Bdim; ++b) {
        float v = x[(size_t)b * CLn + f];
        sum += v; sumsq += v * v;
    }
    float mu  = sum * (1.f / Bdim);
    float var = fmaxf(sumsq * (1.f / Bdim) - mu * mu, 0.f);
    float sc  = bn_g[f] / sqrtf(var + 1e-5f);
    scale[f] = sc;
    shift[f] = bn_b[f] - mu * sc;
}

__global__ __launch_bounds__(256) void xn_kernel(
    const float* __restrict__ x, const float* __restrict__ scale,
    const float* __restrict__ shift, float* __restrict__ xn)
{
    int idx = blockIdx.x * 256 + threadIdx.x;
    int f = idx % CLn;
    xn[idx] = fmaf(x[idx], scale[f], shift[f]);
}

// ---------------------------------------------------------------------------
// Depthwise conv, stride S, kernel 2S, pad S/2 (cross-correlation, as lax)
// ---------------------------------------------------------------------------
template<int S>
__global__ __launch_bounds__(256) void dwconv_kernel(
    const float* __restrict__ xn, const float* __restrict__ cw,
    float* __restrict__ outp)
{
    const int Ls = Ldim / S;
    int idx = blockIdx.x * 256 + threadIdx.x;
    if (idx >= BC * Ls) return;
    int o = idx % Ls;
    int r = idx / Ls;            // r = b*C + c
    int c = r % Cdim;
    const float* xrow = xn + (size_t)r * Ldim;
    const float* w = cw + c * (2 * S);
    int start = o * S - S / 2;
    float acc = 0.f;
#pragma unroll
    for (int k = 0; k < 2 * S; ++k) {
        int pos = start + k;
        float v = (pos >= 0 && pos < Ldim) ? xrow[pos] : 0.f;
        acc = fmaf(v, w[k], acc);
    }
    outp[idx] = acc;
}

// ---------------------------------------------------------------------------
// EMA along time, replicating the reference's fp32-underflow semantics:
//   trend[t] = (n[t]/d[t]) * min(1, den_true[t]/1e-12)
//   n: EMA recurrence (n[0]=x[0], n[t]=m*n[t-1]+a*x[t]);  d[t]=(1-m^{t+1})/a
//   den_true[t] = m^{Ls-1-t} * d[t]   (computed in log2 domain)
// One wave per row; segmented affine-scan across 64 lanes.
// ---------------------------------------------------------------------------
template<int SEG>
__global__ __launch_bounds__(64) void ema_kernel(
    const float* __restrict__ X, const float* __restrict__ al,
    float* __restrict__ T)
{
    const int Ls = SEG * 64;
    int row  = blockIdx.x;
    int c    = row % Cdim;
    int lane = threadIdx.x;
    float a = (float)(1.0 / (1.0 + exp(-(double)al[c])));
    float m = 1.f - a;
    const float* xr = X + (size_t)row * Ls;
    float xs[SEG];
#pragma unroll
    for (int i = 0; i < SEG; ++i) xs[i] = xr[lane * SEG + i];

    // local affine: y_out = m^SEG * y_in + p
    float p = 0.f;
#pragma unroll
    for (int i = 0; i < SEG; ++i) {
        float bi = a * xs[i];
        if (lane == 0 && i == 0) bi = xs[0];   // w_num[0] has coefficient 1
        p = fmaf(m, p, bi);
    }
    float Sm = powf(m, (float)SEG);
    float Sp = p;
    // inclusive scan of affine composition across lanes
#pragma unroll
    for (int d = 1; d < 64; d <<= 1) {
        float pm = __shfl_up(Sp, d);
        float mm = __shfl_up(Sm, d);
        if (lane >= d) { Sp = fmaf(Sm, pm, Sp); Sm = Sm * mm; }
    }
    float carry = __shfl_up(Sp, 1);
    if (lane == 0) carry = 0.f;

    double log2m = log2((double)m);
    float y  = carry;
    float mp = powf(m, (float)(lane * SEG + 1));  // m^{t+1} at segment start
    float* tr = T + (size_t)row * Ls;
#pragma unroll
    for (int i = 0; i < SEG; ++i) {
        int t = lane * SEG + i;
        float bi = a * xs[i];
        if (lane == 0 && i == 0) bi = xs[0];
        y = fmaf(m, y, bi);
        float dt = (1.f - mp) / a;
        mp *= m;
        // den_true / 1e-12 in log2 domain:  -log2(1e-12) = 39.8631371386
        double arg = (double)(Ls - 1 - t) * log2m + log2((double)dt)
                     + 39.863137138648355;
        float ramp = (arg >= 0.0) ? 1.f : exp2f((float)arg);
        tr[t] = (y / dt) * ramp;
    }
}

// ---------------------------------------------------------------------------
// GEMM1 (fp32 A,B): H = gelu(A(MxK) * B(NxK)^T + bias), output bf16.
// M=2*BC fixed, N=1024 fixed. 128x128 tile, BK=8, 256 threads, 8x8/thread.
// ---------------------------------------------------------------------------
#define GBM 128
#define GBN 128
#define GBK 8

__global__ __launch_bounds__(256) void gemm1_kernel(
    const float* __restrict__ A, const float* __restrict__ Bw,
    const float* __restrict__ bias, __hip_bfloat16* __restrict__ H, int K)
{
    __shared__ float As[GBK][GBM + 4];
    __shared__ float Bs[GBK][GBN + 4];
    int tid = threadIdx.x;
    int m0 = blockIdx.y * GBM, n0 = blockIdx.x * GBN;
    int tm = tid / 16, tn = tid % 16;
    int lr = tid / 2;            // 0..127 tile row
    int lk = (tid % 2) * 4;      // k sub-offset 0 or 4
    float acc[8][8] = {{0.f}};

    for (int k0 = 0; k0 < K; k0 += GBK) {
        float4 a4 = *(const float4*)(A  + (size_t)(m0 + lr) * K + k0 + lk);
        float4 b4 = *(const float4*)(Bw + (size_t)(n0 + lr) * K + k0 + lk);
        __syncthreads();
        As[lk + 0][lr] = a4.x; As[lk + 1][lr] = a4.y;
        As[lk + 2][lr] = a4.z; As[lk + 3][lr] = a4.w;
        Bs[lk + 0][lr] = b4.x; Bs[lk + 1][lr] = b4.y;
        Bs[lk + 2][lr] = b4.z; Bs[lk + 3][lr] = b4.w;
        __syncthreads();
#pragma unroll
        for (int kk = 0; kk < GBK; ++kk) {
            float ar[8], br[8];
            *(float4*)&ar[0] = *(const float4*)&As[kk][tm * 8];
            *(float4*)&ar[4] = *(const float4*)&As[kk][tm * 8 + 4];
            *(float4*)&br[0] = *(const float4*)&Bs[kk][tn * 8];
            *(float4*)&br[4] = *(const float4*)&Bs[kk][tn * 8 + 4];
#pragma unroll
            for (int i = 0; i < 8; ++i)
#pragma unroll
                for (int j = 0; j < 8; ++j)
                    acc[i][j] = fmaf(ar[i], br[j], acc[i][j]);
        }
    }
#pragma unroll
    for (int i = 0; i < 8; ++i) {
        size_t mrow = m0 + tm * 8 + i;
#pragma unroll
        for (int j = 0; j < 8; ++j) {
            int ncol = n0 + tn * 8 + j;
            float z = acc[i][j] + bias[ncol];
            z = 0.5f * z * (1.f + erff(z * 0.70710678118654752f));
            H[mrow * 1024 + ncol] = __float2bfloat16(z);
        }
    }
}

// ---------------------------------------------------------------------------
// GEMM2 (bf16 A, fp32 B): Z = A(2BCx1024) * W2(1024x1024)^T, fused epilogue:
//   up rows    (m < BC):  season[r, n] += g * Z
//   trend rows (m >= BC): season[r, n] -= g * Z ; trend[r, n] += g*(Z + b2[n])
// (b2 cancels inside season = U - T.)
// ---------------------------------------------------------------------------
__global__ __launch_bounds__(256) void gemm2_kernel(
    const ushort_t* __restrict__ A, const float* __restrict__ Bw,
    const float* __restrict__ b2, const float* __restrict__ g, int si,
    float* __restrict__ out)
{
    __shared__ float As[GBK][GBM + 4];
    __shared__ float Bs[GBK][GBN + 4];
    int tid = threadIdx.x;
    int m0 = blockIdx.y * GBM, n0 = blockIdx.x * GBN;
    int tm = tid / 16, tn = tid % 16;
    int lr = tid / 2;
    int lk = (tid % 2) * 4;
    float acc[8][8] = {{0.f}};
    const int K = 1024;

    for (int k0 = 0; k0 < K; k0 += GBK) {
        const ushort_t* ap = A + (size_t)(m0 + lr) * K + k0 + lk;
        ushort_t a0 = ap[0], a1 = ap[1], a2 = ap[2], a3 = ap[3];
        float4 b4 = *(const float4*)(Bw + (size_t)(n0 + lr) * K + k0 + lk);
        __syncthreads();
        As[lk + 0][lr] = bf2f(a0); As[lk + 1][lr] = bf2f(a1);
        As[lk + 2][lr] = bf2f(a2); As[lk + 3][lr] = bf2f(a3);
        Bs[lk + 0][lr] = b4.x; Bs[lk + 1][lr] = b4.y;
        Bs[lk + 2][lr] = b4.z; Bs[lk + 3][lr] = b4.w;
        __syncthreads();
#pragma unroll
        for (int kk = 0; kk < GBK; ++kk) {
            float ar[8], br[8];
            *(float4*)&ar[0] = *(const float4*)&As[kk][tm * 8];
            *(float4*)&ar[4] = *(const float4*)&As[kk][tm * 8 + 4];
            *(float4*)&br[0] = *(const float4*)&Bs[kk][tn * 8];
            *(float4*)&br[4] = *(const float4*)&Bs[kk][tn * 8 + 4];
#pragma unroll
            for (int i = 0; i < 8; ++i)
#pragma unroll
                for (int j = 0; j < 8; ++j)
                    acc[i][j] = fmaf(ar[i], br[j], acc[i][j]);
        }
    }
    // epilogue: whole 128-row tile is one batch, one side (up/trend)
    int is_trend = (m0 >= BC);
    int r0 = m0 - (is_trend ? BC : 0);
    float gval = g[(r0 / Cdim) * 4 + si];
    float* season = out;
    float* trend  = out + TOT;
#pragma unroll
    for (int i = 0; i < 8; ++i) {
        size_t r = r0 + tm * 8 + i;
#pragma unroll
        for (int j = 0; j < 8; ++j) {
            int ncol = n0 + tn * 8 + j;
            size_t idx = r * 1024 + ncol;
            float z = acc[i][j];
            if (!is_trend) {
                season[idx] += gval * z;
            } else {
                season[idx] -= gval * z;
                trend[idx]  += gval * (z + b2[ncol]);
            }
        }
    }
}

// ---------------------------------------------------------------------------
// column sums of the three W2 matrices (for the gate matvec trick)
// ---------------------------------------------------------------------------
__global__ __launch_bounds__(256) void w2colsum_kernel(
    const float* __restrict__ w2_8, const float* __restrict__ w2_4,
    const float* __restrict__ w2_2, float* __restrict__ w2cs)
{
    int h = blockIdx.x * 256 + threadIdx.x;   // h < 1024
    const float* w = (blockIdx.y == 0) ? w2_8 : (blockIdx.y == 1) ? w2_4 : w2_2;
    float s = 0.f;
    for (int l = 0; l < 1024; ++l) s += w[(size_t)l * 1024 + h];
    w2cs[blockIdx.y * 1024 + h] = s;
}

// ---------------------------------------------------------------------------
// season row-sum via H matvec: rs[r] = sum_h (H[r,h]-H[r+BC,h]) * w2cs[h]
// ---------------------------------------------------------------------------
__global__ __launch_bounds__(256) void rowsum_h_kernel(
    const ushort_t* __restrict__ H, const float* __restrict__ w2cs,
    float* __restrict__ rs)
{
    int r = blockIdx.x, tid = threadIdx.x;
    const ushort_t* hu = H + (size_t)r * 1024;
    const ushort_t* ht = hu + (size_t)BC * 1024;
    float s = 0.f;
    for (int h = tid; h < 1024; h += 256)
        s += (bf2f(hu[h]) - bf2f(ht[h])) * w2cs[h];
#pragma unroll
    for (int d = 32; d > 0; d >>= 1) s += __shfl_down(s, d);
    __shared__ float red[4];
    if ((tid & 63) == 0) red[tid >> 6] = s;
    __syncthreads();
    if (tid == 0) rs[r] = red[0] + red[1] + red[2] + red[3];
}

// season row-sum for scale 1: sum_l (xn - t1)
__global__ __launch_bounds__(256) void rowdiff_sum_kernel(
    const float* __restrict__ Up, const float* __restrict__ Tp,
    float* __restrict__ rs)
{
    int r = blockIdx.x, tid = threadIdx.x;
    const float* ur = Up + (size_t)r * Ldim;
    const float* tr = Tp + (size_t)r * Ldim;
    float s = 0.f;
    for (int l = tid; l < Ldim; l += 256) s += ur[l] - tr[l];
#pragma unroll
    for (int d = 32; d > 0; d >>= 1) s += __shfl_down(s, d);
    __shared__ float red[4];
    if ((tid & 63) == 0) red[tid >> 6] = s;
    __syncthreads();
    if (tid == 0) rs[r] = red[0] + red[1] + red[2] + red[3];
}

// ---------------------------------------------------------------------------
// gates: sigmoid(mean_L(season) . gw + gb) per scale, then normalize over 4
// ---------------------------------------------------------------------------
__global__ __launch_bounds__(128) void gate_kernel(
    const float* __restrict__ rs,
    const float* __restrict__ gw8, const float* __restrict__ gb8,
    const float* __restrict__ gw4, const float* __restrict__ gb4,
    const float* __restrict__ gw2, const float* __restrict__ gb2,
    const float* __restrict__ gw1, const float* __restrict__ gb1,
    float* __restrict__ g)
{
    int b = blockIdx.x;
    int c = threadIdx.x;
    const float* gws[4] = {gw8, gw4, gw2, gw1};
    const float* gbs[4] = {gb8, gb4, gb2, gb1};
    __shared__ float buf[128];
    __shared__ float gates[4];
    for (int si = 0; si < 4; ++si) {
        buf[c] = rs[si * BC + b * Cdim + c] * (1.f / Ldim) * gws[si][c];
        __syncthreads();
        for (int off = 64; off >= 1; off >>= 1) {
            if (c < off) buf[c] += buf[c + off];
            __syncthreads();
        }
        if (c == 0) {
            float z = buf[0] + gbs[si][0];
            gates[si] = 1.f / (1.f + expf(-z));
        }
        __syncthreads();
    }
    if (c == 0) {
        float s = gates[0] + gates[1] + gates[2] + gates[3] + 1e-6f;
#pragma unroll
        for (int si = 0; si < 4; ++si) g[b * 4 + si] = gates[si] / s;
    }
}

// ---------------------------------------------------------------------------
// init d_out with the scale-1 contribution (overwrites the conv scratch that
// was aliased there): season = g1*(xn-t1), trend = g1*t1
// ---------------------------------------------------------------------------
__global__ __launch_bounds__(256) void init_out_kernel(
    const float* __restrict__ xn, const float* __restrict__ t1,
    const float* __restrict__ g, float* __restrict__ out)
{
    int idx = blockIdx.x * 256 + threadIdx.x;
    int b = idx / CLn;
    float g1 = g[b * 4 + 3];
    float xv = xn[idx], tv = t1[idx];
    out[idx]       = g1 * (xv - tv);
    out[TOT + idx] = g1 * tv;
}

// ---------------------------------------------------------------------------
extern "C" void kernel_launch(void* const* d_in, const int* in_sizes, int n_in,
                              void* d_out, int out_size, void* d_ws, size_t ws_size,
                              hipStream_t stream)
{
    const float* x    = (const float*)d_in[0];
    const float* bn_g = (const float*)d_in[1];
    const float* bn_b = (const float*)d_in[2];
    const float* cw8  = (const float*)d_in[3];
    const float* w1_8 = (const float*)d_in[4];
    const float* b1_8 = (const float*)d_in[5];
    const float* w2_8 = (const float*)d_in[6];
    const float* b2_8 = (const float*)d_in[7];
    const float* cw4  = (const float*)d_in[8];
    const float* w1_4 = (const float*)d_in[9];
    const float* b1_4 = (const float*)d_in[10];
    const float* w2_4 = (const float*)d_in[11];
    const float* b2_4 = (const float*)d_in[12];
    const float* cw2  = (const float*)d_in[13];
    const float* w1_2 = (const float*)d_in[14];
    const float* b1_2 = (const float*)d_in[15];
    const float* w2_2 = (const float*)d_in[16];
    const float* b2_2 = (const float*)d_in[17];
    const float* gw8  = (const float*)d_in[18];
    const float* gb8  = (const float*)d_in[19];
    const float* al8  = (const float*)d_in[20];
    const float* gw4  = (const float*)d_in[21];
    const float* gb4  = (const float*)d_in[22];
    const float* al4  = (const float*)d_in[23];
    const float* gw2  = (const float*)d_in[24];
    const float* gb2  = (const float*)d_in[25];
    const float* al2  = (const float*)d_in[26];
    const float* gw1  = (const float*)d_in[27];
    const float* gb1  = (const float*)d_in[28];
    const float* al1  = (const float*)d_in[29];

    // workspace layout (~169 MB): xn, t1 fp32; H8/H4/H2 bf16 (2*TOT each)
    float*    p_xn = (float*)d_ws;                    // TOT
    float*    p_t1 = p_xn + TOT;                      // TOT
    ushort_t* p_H8 = (ushort_t*)(p_t1 + TOT);         // 2*TOT bf16
    ushort_t* p_H4 = p_H8 + 2 * (size_t)TOT;          // 2*TOT bf16
    ushort_t* p_H2 = p_H4 + 2 * (size_t)TOT;          // 2*TOT bf16
    float*    p_sc = (float*)(p_H2 + 2 * (size_t)TOT); // CLn
    float*    p_sh = p_sc + CLn;                      // CLn
    float*    p_w2cs = p_sh + CLn;                    // 3*1024
    float*    p_rs = p_w2cs + 3 * 1024;               // 4*BC
    float*    p_g  = p_rs + 4 * BC;                   // 256
    // conv/EMA scratch aliased into d_out (dead until init_out)
    float*    p_D  = (float*)d_out;                   // up to 2*BC*512

    bn_stats_kernel<<<CLn / 256, 256, 0, stream>>>(x, bn_g, bn_b, p_sc, p_sh);
    xn_kernel<<<TOT / 256, 256, 0, stream>>>(x, p_sc, p_sh, p_xn);
    ema_kernel<16><<<BC, 64, 0, stream>>>(p_xn, al1, p_t1);

    dim3 gg(1024 / GBN, 2 * BC / GBM);   // (8, 128)

    // scale 8
    dwconv_kernel<8><<<BC * 128 / 256, 256, 0, stream>>>(p_xn, cw8, p_D);
    ema_kernel<2><<<BC, 64, 0, stream>>>(p_D, al8, p_D + (size_t)BC * 128);
    gemm1_kernel<<<gg, 256, 0, stream>>>(p_D, w1_8, b1_8, (__hip_bfloat16*)p_H8, 128);
    // scale 4
    dwconv_kernel<4><<<BC * 256 / 256, 256, 0, stream>>>(p_xn, cw4, p_D);
    ema_kernel<4><<<BC, 64, 0, stream>>>(p_D, al4, p_D + (size_t)BC * 256);
    gemm1_kernel<<<gg, 256, 0, stream>>>(p_D, w1_4, b1_4, (__hip_bfloat16*)p_H4, 256);
    // scale 2
    dwconv_kernel<2><<<BC * 512 / 256, 256, 0, stream>>>(p_xn, cw2, p_D);
    ema_kernel<8><<<BC, 64, 0, stream>>>(p_D, al2, p_D + (size_t)BC * 512);
    gemm1_kernel<<<gg, 256, 0, stream>>>(p_D, w1_2, b1_2, (__hip_bfloat16*)p_H2, 512);

    // gates (matvec trick — no U/T materialization needed)
    w2colsum_kernel<<<dim3(4, 3), 256, 0, stream>>>(w2_8, w2_4, w2_2, p_w2cs);
    rowsum_h_kernel<<<BC, 256, 0, stream>>>(p_H8, p_w2cs + 0,    p_rs + 0 * BC);
    rowsum_h_kernel<<<BC, 256, 0, stream>>>(p_H4, p_w2cs + 1024, p_rs + 1 * BC);
    rowsum_h_kernel<<<BC, 256, 0, stream>>>(p_H2, p_w2cs + 2048, p_rs + 2 * BC);
    rowdiff_sum_kernel<<<BC, 256, 0, stream>>>(p_xn, p_t1, p_rs + 3 * BC);
    gate_kernel<<<Bdim, 128, 0, stream>>>(p_rs, gw8, gb8, gw4, gb4,
                                          gw2, gb2, gw1, gb1, p_g);

    // output: init with scale-1 term, then accumulate g-weighted GEMM2s
    init_out_kernel<<<TOT / 256, 256, 0, stream>>>(p_xn, p_t1, p_g, (float*)d_out);
    gemm2_kernel<<<gg, 256, 0, stream>>>(p_H8, w2_8, b2_8, p_g, 0, (float*)d_out);
    gemm2_kernel<<<gg, 256, 0, stream>>>(p_H4, w2_4, b2_4, p_g, 1, (float*)d_out);
    gemm2_kernel<<<gg, 256, 0, stream>>>(p_H2, w2_2, b2_2, p_g, 2, (float*)d_out);
}

// Round 3
// 799.723 us; speedup vs baseline: 2.6882x; 2.6882x over previous
//
#include <hip/hip_runtime.h>
#include <hip/hip_bf16.h>
#include <math.h>

// Problem constants
#define Bdim 64
#define Cdim 128
#define Ldim 1024
#define BC   (Bdim * Cdim)      // 8192 rows
#define CLn  (Cdim * Ldim)      // 131072 features
#define TOT  (Bdim * CLn)       // 8388608 elements per (B,C,L) tensor

typedef unsigned short ushort_t;
typedef short s16x8 __attribute__((ext_vector_type(8)));   // 8 bf16 (4 VGPRs)
typedef float f32x4 __attribute__((ext_vector_type(4)));

__device__ __forceinline__ float bf2f(ushort_t u) {
    return __uint_as_float(((unsigned)u) << 16);
}
__device__ __forceinline__ ushort_t f2bf(float f) {
    __hip_bfloat16 h = __float2bfloat16(f);
    return *(ushort_t*)&h;
}
// async global->LDS, 16B per lane; lds base must be wave-uniform,
// lane i lands at base + i*16B.
__device__ __forceinline__ void async16(const ushort_t* g, ushort_t* l) {
    __builtin_amdgcn_global_load_lds(
        (const __attribute__((address_space(1))) unsigned int*)g,
        (__attribute__((address_space(3))) unsigned int*)l, 16, 0, 0);
}

// load/store helpers (fp32 or bf16 storage)
__device__ __forceinline__ float ldf(const float* p, size_t i) { return p[i]; }
__device__ __forceinline__ float ldf(const ushort_t* p, size_t i) { return bf2f(p[i]); }
__device__ __forceinline__ void stf(float* p, size_t i, float v) { p[i] = v; }
__device__ __forceinline__ void stf(ushort_t* p, size_t i, float v) { p[i] = f2bf(v); }

// ---------------------------------------------------------------------------
// BN: per-feature mean/var over batch axis -> fused scale/shift
// ---------------------------------------------------------------------------
__global__ __launch_bounds__(256) void bn_stats_kernel(
    const float* __restrict__ x, const float* __restrict__ bn_g,
    const float* __restrict__ bn_b, float* __restrict__ scale,
    float* __restrict__ shift)
{
    int f = blockIdx.x * 256 + threadIdx.x;
    float sum = 0.f, sumsq = 0.f;
    for (int b = 0; b < Bdim; ++b) {
        float v = x[(size_t)b * CLn + f];
        sum += v; sumsq += v * v;
    }
    float mu  = sum * (1.f / Bdim);
    float var = fmaxf(sumsq * (1.f / Bdim) - mu * mu, 0.f);
    float sc  = bn_g[f] / sqrtf(var + 1e-5f);
    scale[f] = sc;
    shift[f] = bn_b[f] - mu * sc;
}

__global__ __launch_bounds__(256) void xn_kernel(
    const float* __restrict__ x, const float* __restrict__ scale,
    const float* __restrict__ shift, float* __restrict__ xn)
{
    int idx = blockIdx.x * 256 + threadIdx.x;
    int f = idx % CLn;
    xn[idx] = fmaf(x[idx], scale[f], shift[f]);
}

// ---------------------------------------------------------------------------
// fp32 -> bf16 weight conversion (all 6 weight matrices, one launch)
// layout in dst: w1b8 | w1b4 | w1b2 | w2b8 | w2b4 | w2b2
// ---------------------------------------------------------------------------
__global__ __launch_bounds__(256) void convert_weights_kernel(
    const float* __restrict__ w1_8, const float* __restrict__ w1_4,
    const float* __restrict__ w1_2, const float* __restrict__ w2_8,
    const float* __restrict__ w2_4, const float* __restrict__ w2_2,
    ushort_t* __restrict__ dst)
{
    int idx = blockIdx.x * 256 + threadIdx.x;   // < 4063232 exact
    const float* src; int off;
    if      (idx < 131072)  { src = w1_8; off = 0; }
    else if (idx < 393216)  { src = w1_4; off = 131072; }
    else if (idx < 917504)  { src = w1_2; off = 393216; }
    else if (idx < 1966080) { src = w2_8; off = 917504; }
    else if (idx < 3014656) { src = w2_4; off = 1966080; }
    else                    { src = w2_2; off = 3014656; }
    dst[idx] = f2bf(src[idx - off]);
}

// ---------------------------------------------------------------------------
// Depthwise conv, stride S, kernel 2S, pad S/2; fp32 in, bf16 out
// ---------------------------------------------------------------------------
template<int S>
__global__ __launch_bounds__(256) void dwconv_kernel(
    const float* __restrict__ xn, const float* __restrict__ cw,
    ushort_t* __restrict__ outp)
{
    const int Ls = Ldim / S;
    int idx = blockIdx.x * 256 + threadIdx.x;
    if (idx >= BC * Ls) return;
    int o = idx % Ls;
    int r = idx / Ls;
    int c = r % Cdim;
    const float* xrow = xn + (size_t)r * Ldim;
    const float* w = cw + c * (2 * S);
    int start = o * S - S / 2;
    float acc = 0.f;
#pragma unroll
    for (int k = 0; k < 2 * S; ++k) {
        int pos = start + k;
        float v = (pos >= 0 && pos < Ldim) ? xrow[pos] : 0.f;
        acc = fmaf(v, w[k], acc);
    }
    outp[idx] = f2bf(acc);
}

// ---------------------------------------------------------------------------
// EMA along time (reference fp32-underflow semantics, see round 0 notes).
// One wave per row; segmented affine-scan across 64 lanes.
// ---------------------------------------------------------------------------
template<int SEG, typename T>
__global__ __launch_bounds__(64) void ema_kernel(
    const T* __restrict__ X, const float* __restrict__ al,
    T* __restrict__ Tout)
{
    const int Ls = SEG * 64;
    int row  = blockIdx.x;
    int c    = row % Cdim;
    int lane = threadIdx.x;
    float a = (float)(1.0 / (1.0 + exp(-(double)al[c])));
    float m = 1.f - a;
    const T* xr = X + (size_t)row * Ls;
    float xs[SEG];
#pragma unroll
    for (int i = 0; i < SEG; ++i) xs[i] = ldf(xr, lane * SEG + i);

    float p = 0.f;
#pragma unroll
    for (int i = 0; i < SEG; ++i) {
        float bi = a * xs[i];
        if (lane == 0 && i == 0) bi = xs[0];
        p = fmaf(m, p, bi);
    }
    float Sm = powf(m, (float)SEG);
    float Sp = p;
#pragma unroll
    for (int d = 1; d < 64; d <<= 1) {
        float pm = __shfl_up(Sp, d);
        float mm = __shfl_up(Sm, d);
        if (lane >= d) { Sp = fmaf(Sm, pm, Sp); Sm = Sm * mm; }
    }
    float carry = __shfl_up(Sp, 1);
    if (lane == 0) carry = 0.f;

    double log2m = log2((double)m);
    float y  = carry;
    float mp = powf(m, (float)(lane * SEG + 1));
    T* tr = Tout + (size_t)row * Ls;
#pragma unroll
    for (int i = 0; i < SEG; ++i) {
        int t = lane * SEG + i;
        float bi = a * xs[i];
        if (lane == 0 && i == 0) bi = xs[0];
        y = fmaf(m, y, bi);
        float dt = (1.f - mp) / a;
        mp *= m;
        double arg = (double)(Ls - 1 - t) * log2m + log2((double)dt)
                     + 39.863137138648355;   // -log2(1e-12)
        float ramp = (arg >= 0.0) ? 1.f : exp2f((float)arg);
        stf(tr, t, (y / dt) * ramp);
    }
}

// ---------------------------------------------------------------------------
// bf16 MFMA NT GEMM: C(MxN=1024) = A(MxK) * B(1024xK)^T
// 128x128 block tile, 4 waves x (64x64), BK=64, 16x16x32 MFMA.
// global_load_lds staging with k-chunk rotate swizzle:
//   logical k-chunk lc of row r stored at physical chunk pc = (lc + r) & 7
// EPI=0: H = bf16(gelu(C + b1))     EPI=1: g-weighted accumulate into out
// ---------------------------------------------------------------------------
template<int EPI>
__global__ __launch_bounds__(256) void mfma_gemm_kernel(
    const ushort_t* __restrict__ A, const ushort_t* __restrict__ Bw,
    const float* __restrict__ bias, const float* __restrict__ g,
    int K, int si, ushort_t* __restrict__ Hout, float* __restrict__ out)
{
    __shared__ ushort_t As[128 * 64];
    __shared__ ushort_t Bs[128 * 64];
    int tid  = threadIdx.x;
    int wave = tid >> 6;
    int lane = tid & 63;
    int m0 = blockIdx.y * 128, n0 = blockIdx.x * 128;
    int wm = (wave & 1) * 64, wn = (wave >> 1) * 64;
    int lrow = lane >> 3;      // staging: row within 8-row group
    int pc   = lane & 7;       // staging: physical chunk
    int fr   = lane & 15;      // fragment row/col
    int quad = lane >> 4;

    f32x4 acc[4][4];
#pragma unroll
    for (int i = 0; i < 4; ++i)
#pragma unroll
        for (int j = 0; j < 4; ++j) acc[i][j] = (f32x4){0.f, 0.f, 0.f, 0.f};

    for (int k0 = 0; k0 < K; k0 += 64) {
        __syncthreads();   // previous stage's ds_reads done before overwrite
#pragma unroll
        for (int i = 0; i < 4; ++i) {
            int rb  = wave * 32 + i * 8;
            int row = rb + lrow;
            int lc  = (pc - row) & 7;
            async16(A  + (size_t)(m0 + row) * K + k0 + lc * 8, &As[rb * 64]);
            async16(Bw + (size_t)(n0 + row) * K + k0 + lc * 8, &Bs[rb * 64]);
        }
        __syncthreads();   // vmcnt drained -> LDS data visible
#pragma unroll
        for (int kk = 0; kk < 64; kk += 32) {
            s16x8 af[4], bfr[4];
            int lcA = (kk >> 3) + quad;
#pragma unroll
            for (int t = 0; t < 4; ++t) {
                int mr  = wm + t * 16 + fr;
                int pcA = (lcA + mr) & 7;
                af[t]  = *(const s16x8*)&As[mr * 64 + pcA * 8];
                int nr  = wn + t * 16 + fr;
                int pcB = (lcA + nr) & 7;
                bfr[t] = *(const s16x8*)&Bs[nr * 64 + pcB * 8];
            }
#pragma unroll
            for (int mt = 0; mt < 4; ++mt)
#pragma unroll
                for (int nt = 0; nt < 4; ++nt)
                    acc[mt][nt] = __builtin_amdgcn_mfma_f32_16x16x32_bf16(
                        af[mt], bfr[nt], acc[mt][nt], 0, 0, 0);
        }
    }

    // epilogue — D layout: m = quad*4 + reg, n = lane&15  (verified m89/m91)
    if (EPI == 0) {
#pragma unroll
        for (int mt = 0; mt < 4; ++mt)
#pragma unroll
            for (int nt = 0; nt < 4; ++nt) {
                int col = n0 + wn + nt * 16 + fr;
#pragma unroll
                for (int r = 0; r < 4; ++r) {
                    size_t row = m0 + wm + mt * 16 + quad * 4 + r;
                    float z = acc[mt][nt][r] + bias[col];
                    z = 0.5f * z * (1.f + erff(z * 0.70710678118654752f));
                    Hout[row * 1024 + col] = f2bf(z);
                }
            }
    } else {
        int is_trend = (m0 >= BC);
        int r0 = m0 - (is_trend ? BC : 0);
        float gval = g[(r0 >> 7) * 4 + si];   // 128 rows = one (batch, side)
        float* season = out;
        float* trend  = out + TOT;
#pragma unroll
        for (int mt = 0; mt < 4; ++mt)
#pragma unroll
            for (int nt = 0; nt < 4; ++nt) {
                int col = n0 + wn + nt * 16 + fr;
#pragma unroll
                for (int r = 0; r < 4; ++r) {
                    size_t row = r0 + wm + mt * 16 + quad * 4 + r;
                    size_t idx = row * 1024 + col;
                    float z = acc[mt][nt][r];
                    if (!is_trend) {
                        season[idx] += gval * z;
                    } else {
                        season[idx] -= gval * z;
                        trend[idx]  += gval * (z + bias[col]);
                    }
                }
            }
    }
}

// ---------------------------------------------------------------------------
// column sums of the three W2 matrices (gate matvec trick)
// ---------------------------------------------------------------------------
__global__ __launch_bounds__(256) void w2colsum_kernel(
    const float* __restrict__ w2_8, const float* __restrict__ w2_4,
    const float* __restrict__ w2_2, float* __restrict__ w2cs)
{
    int h = blockIdx.x * 256 + threadIdx.x;
    const float* w = (blockIdx.y == 0) ? w2_8 : (blockIdx.y == 1) ? w2_4 : w2_2;
    float s = 0.f;
    for (int l = 0; l < 1024; ++l) s += w[(size_t)l * 1024 + h];
    w2cs[blockIdx.y * 1024 + h] = s;
}

// season row-sum via H matvec: rs[r] = sum_h (H[r,h]-H[r+BC,h]) * w2cs[h]
__global__ __launch_bounds__(256) void rowsum_h_kernel(
    const ushort_t* __restrict__ H, const float* __restrict__ w2cs,
    float* __restrict__ rs)
{
    int r = blockIdx.x, tid = threadIdx.x;
    const ushort_t* hu = H + (size_t)r * 1024;
    const ushort_t* ht = hu + (size_t)BC * 1024;
    float s = 0.f;
    for (int h = tid; h < 1024; h += 256)
        s += (bf2f(hu[h]) - bf2f(ht[h])) * w2cs[h];
#pragma unroll
    for (int d = 32; d > 0; d >>= 1) s += __shfl_down(s, d);
    __shared__ float red[4];
    if ((tid & 63) == 0) red[tid >> 6] = s;
    __syncthreads();
    if (tid == 0) rs[r] = red[0] + red[1] + red[2] + red[3];
}

// season row-sum for scale 1: sum_l (xn - t1)
__global__ __launch_bounds__(256) void rowdiff_sum_kernel(
    const float* __restrict__ Up, const float* __restrict__ Tp,
    float* __restrict__ rs)
{
    int r = blockIdx.x, tid = threadIdx.x;
    const float* ur = Up + (size_t)r * Ldim;
    const float* tr = Tp + (size_t)r * Ldim;
    float s = 0.f;
    for (int l = tid; l < Ldim; l += 256) s += ur[l] - tr[l];
#pragma unroll
    for (int d = 32; d > 0; d >>= 1) s += __shfl_down(s, d);
    __shared__ float red[4];
    if ((tid & 63) == 0) red[tid >> 6] = s;
    __syncthreads();
    if (tid == 0) rs[r] = red[0] + red[1] + red[2] + red[3];
}

// ---------------------------------------------------------------------------
// gates: sigmoid(mean_L(season) . gw + gb) per scale, then normalize over 4
// ---------------------------------------------------------------------------
__global__ __launch_bounds__(128) void gate_kernel(
    const float* __restrict__ rs,
    const float* __restrict__ gw8, const float* __restrict__ gb8,
    const float* __restrict__ gw4, const float* __restrict__ gb4,
    const float* __restrict__ gw2, const float* __restrict__ gb2,
    const float* __restrict__ gw1, const float* __restrict__ gb1,
    float* __restrict__ g)
{
    int b = blockIdx.x;
    int c = threadIdx.x;
    const float* gws[4] = {gw8, gw4, gw2, gw1};
    const float* gbs[4] = {gb8, gb4, gb2, gb1};
    __shared__ float buf[128];
    __shared__ float gates[4];
    for (int si = 0; si < 4; ++si) {
        buf[c] = rs[si * BC + b * Cdim + c] * (1.f / Ldim) * gws[si][c];
        __syncthreads();
        for (int off = 64; off >= 1; off >>= 1) {
            if (c < off) buf[c] += buf[c + off];
            __syncthreads();
        }
        if (c == 0) {
            float z = buf[0] + gbs[si][0];
            gates[si] = 1.f / (1.f + expf(-z));
        }
        __syncthreads();
    }
    if (c == 0) {
        float s = gates[0] + gates[1] + gates[2] + gates[3] + 1e-6f;
#pragma unroll
        for (int si = 0; si < 4; ++si) g[b * 4 + si] = gates[si] / s;
    }
}

// ---------------------------------------------------------------------------
// init d_out with the scale-1 contribution (overwrites A-tile scratch there)
// ---------------------------------------------------------------------------
__global__ __launch_bounds__(256) void init_out_kernel(
    const float* __restrict__ xn, const float* __restrict__ t1,
    const float* __restrict__ g, float* __restrict__ out)
{
    int idx = blockIdx.x * 256 + threadIdx.x;
    int b = idx / CLn;
    float g1 = g[b * 4 + 3];
    float xv = xn[idx], tv = t1[idx];
    out[idx]       = g1 * (xv - tv);
    out[TOT + idx] = g1 * tv;
}

// ---------------------------------------------------------------------------
extern "C" void kernel_launch(void* const* d_in, const int* in_sizes, int n_in,
                              void* d_out, int out_size, void* d_ws, size_t ws_size,
                              hipStream_t stream)
{
    const float* x    = (const float*)d_in[0];
    const float* bn_g = (const float*)d_in[1];
    const float* bn_b = (const float*)d_in[2];
    const float* cw8  = (const float*)d_in[3];
    const float* w1_8 = (const float*)d_in[4];
    const float* b1_8 = (const float*)d_in[5];
    const float* w2_8 = (const float*)d_in[6];
    const float* b2_8 = (const float*)d_in[7];
    const float* cw4  = (const float*)d_in[8];
    const float* w1_4 = (const float*)d_in[9];
    const float* b1_4 = (const float*)d_in[10];
    const float* w2_4 = (const float*)d_in[11];
    const float* b2_4 = (const float*)d_in[12];
    const float* cw2  = (const float*)d_in[13];
    const float* w1_2 = (const float*)d_in[14];
    const float* b1_2 = (const float*)d_in[15];
    const float* w2_2 = (const float*)d_in[16];
    const float* b2_2 = (const float*)d_in[17];
    const float* gw8  = (const float*)d_in[18];
    const float* gb8  = (const float*)d_in[19];
    const float* al8  = (const float*)d_in[20];
    const float* gw4  = (const float*)d_in[21];
    const float* gb4  = (const float*)d_in[22];
    const float* al4  = (const float*)d_in[23];
    const float* gw2  = (const float*)d_in[24];
    const float* gb2  = (const float*)d_in[25];
    const float* al2  = (const float*)d_in[26];
    const float* gw1  = (const float*)d_in[27];
    const float* gb1  = (const float*)d_in[28];
    const float* al1  = (const float*)d_in[29];

    // workspace (~172 MB)
    float*    p_xn  = (float*)d_ws;                    // TOT
    float*    p_t1  = p_xn + TOT;                      // TOT
    ushort_t* p_H8  = (ushort_t*)(p_t1 + TOT);         // 2*TOT bf16
    ushort_t* p_H4  = p_H8 + 2 * (size_t)TOT;
    ushort_t* p_H2  = p_H4 + 2 * (size_t)TOT;
    ushort_t* p_wb  = p_H2 + 2 * (size_t)TOT;          // 4063232 bf16 weights
    ushort_t* p_w1b8 = p_wb;                           // 1024x128
    ushort_t* p_w1b4 = p_wb + 131072;                  // 1024x256
    ushort_t* p_w1b2 = p_wb + 393216;                  // 1024x512
    ushort_t* p_w2b8 = p_wb + 917504;                  // 1024x1024
    ushort_t* p_w2b4 = p_wb + 1966080;
    ushort_t* p_w2b2 = p_wb + 3014656;
    float*    p_sc  = (float*)(p_wb + 4063232);        // CLn
    float*    p_sh  = p_sc + CLn;                      // CLn
    float*    p_w2cs = p_sh + CLn;                     // 3*1024
    float*    p_rs  = p_w2cs + 3 * 1024;               // 4*BC
    float*    p_g   = p_rs + 4 * BC;                   // 256
    // A-tiles (bf16 down|trend per scale) aliased into d_out (28 MB < 64 MB)
    ushort_t* p_A8 = (ushort_t*)d_out;                 // 2*BC*128
    ushort_t* p_A4 = p_A8 + 2 * (size_t)BC * 128;      // 2*BC*256
    ushort_t* p_A2 = p_A4 + 2 * (size_t)BC * 256;      // 2*BC*512

    bn_stats_kernel<<<CLn / 256, 256, 0, stream>>>(x, bn_g, bn_b, p_sc, p_sh);
    xn_kernel<<<TOT / 256, 256, 0, stream>>>(x, p_sc, p_sh, p_xn);
    ema_kernel<16, float><<<BC, 64, 0, stream>>>(p_xn, al1, p_t1);
    convert_weights_kernel<<<4063232 / 256, 256, 0, stream>>>(
        w1_8, w1_4, w1_2, w2_8, w2_4, w2_2, p_wb);
    w2colsum_kernel<<<dim3(4, 3), 256, 0, stream>>>(w2_8, w2_4, w2_2, p_w2cs);

    dim3 gg(1024 / 128, 2 * BC / 128);   // (8, 128)

    // scale 8
    dwconv_kernel<8><<<BC * 128 / 256, 256, 0, stream>>>(p_xn, cw8, p_A8);
    ema_kernel<2, ushort_t><<<BC, 64, 0, stream>>>(p_A8, al8, p_A8 + (size_t)BC * 128);
    mfma_gemm_kernel<0><<<gg, 256, 0, stream>>>(p_A8, p_w1b8, b1_8, nullptr,
                                                128, 0, p_H8, nullptr);
    rowsum_h_kernel<<<BC, 256, 0, stream>>>(p_H8, p_w2cs + 0, p_rs + 0 * BC);
    // scale 4
    dwconv_kernel<4><<<BC * 256 / 256, 256, 0, stream>>>(p_xn, cw4, p_A4);
    ema_kernel<4, ushort_t><<<BC, 64, 0, stream>>>(p_A4, al4, p_A4 + (size_t)BC * 256);
    mfma_gemm_kernel<0><<<gg, 256, 0, stream>>>(p_A4, p_w1b4, b1_4, nullptr,
                                                256, 0, p_H4, nullptr);
    rowsum_h_kernel<<<BC, 256, 0, stream>>>(p_H4, p_w2cs + 1024, p_rs + 1 * BC);
    // scale 2
    dwconv_kernel<2><<<BC * 512 / 256, 256, 0, stream>>>(p_xn, cw2, p_A2);
    ema_kernel<8, ushort_t><<<BC, 64, 0, stream>>>(p_A2, al2, p_A2 + (size_t)BC * 512);
    mfma_gemm_kernel<0><<<gg, 256, 0, stream>>>(p_A2, p_w1b2, b1_2, nullptr,
                                                512, 0, p_H2, nullptr);
    rowsum_h_kernel<<<BC, 256, 0, stream>>>(p_H2, p_w2cs + 2048, p_rs + 2 * BC);

    rowdiff_sum_kernel<<<BC, 256, 0, stream>>>(p_xn, p_t1, p_rs + 3 * BC);
    gate_kernel<<<Bdim, 128, 0, stream>>>(p_rs, gw8, gb8, gw4, gb4,
                                          gw2, gb2, gw1, gb1, p_g);

    // output: init with scale-1 term, then accumulate g-weighted GEMM2s
    init_out_kernel<<<TOT / 256, 256, 0, stream>>>(p_xn, p_t1, p_g, (float*)d_out);
    mfma_gemm_kernel<1><<<gg, 256, 0, stream>>>(p_H8, p_w2b8, b2_8, p_g,
                                                1024, 0, nullptr, (float*)d_out);
    mfma_gemm_kernel<1><<<gg, 256, 0, stream>>>(p_H4, p_w2b4, b2_4, p_g,
                                                1024, 1, nullptr, (float*)d_out);
    mfma_gemm_kernel<1><<<gg, 256, 0, stream>>>(p_H2, p_w2b2, b2_2, p_g,
                                                1024, 2, nullptr, (float*)d_out);
}

// Round 4
// 745.206 us; speedup vs baseline: 2.8849x; 1.0732x over previous
//
#include <hip/hip_runtime.h>
#include <hip/hip_bf16.h>
#include <math.h>

// Problem constants
#define Bdim 64
#define Cdim 128
#define Ldim 1024
#define BC   (Bdim * Cdim)      // 8192 rows
#define CLn  (Cdim * Ldim)      // 131072 features
#define TOT  (Bdim * CLn)       // 8388608 elements per (B,C,L) tensor

typedef unsigned short ushort_t;
typedef short s16x8 __attribute__((ext_vector_type(8)));   // 8 bf16 (4 VGPRs)
typedef float f32x4 __attribute__((ext_vector_type(4)));

__device__ __forceinline__ float bf2f(ushort_t u) {
    return __uint_as_float(((unsigned)u) << 16);
}
__device__ __forceinline__ ushort_t f2bf(float f) {
    __hip_bfloat16 h = __float2bfloat16(f);
    return *(ushort_t*)&h;
}
// async global->LDS, 16B per lane; lds base wave-uniform, lane i -> base+i*16B
__device__ __forceinline__ void async16(const ushort_t* g, ushort_t* l) {
    __builtin_amdgcn_global_load_lds(
        (const __attribute__((address_space(1))) unsigned int*)g,
        (__attribute__((address_space(3))) unsigned int*)l, 16, 0, 0);
}

__device__ __forceinline__ float ldf(const float* p, size_t i) { return p[i]; }
__device__ __forceinline__ float ldf(const ushort_t* p, size_t i) { return bf2f(p[i]); }
__device__ __forceinline__ void stf(float* p, size_t i, float v) { p[i] = v; }
__device__ __forceinline__ void stf(ushort_t* p, size_t i, float v) { p[i] = f2bf(v); }

// ---------------------------------------------------------------------------
// BN: per-feature mean/var over batch axis -> fused scale/shift
// ---------------------------------------------------------------------------
__global__ __launch_bounds__(256) void bn_stats_kernel(
    const float* __restrict__ x, const float* __restrict__ bn_g,
    const float* __restrict__ bn_b, float* __restrict__ scale,
    float* __restrict__ shift)
{
    int f = blockIdx.x * 256 + threadIdx.x;
    float sum = 0.f, sumsq = 0.f;
    for (int b = 0; b < Bdim; ++b) {
        float v = x[(size_t)b * CLn + f];
        sum += v; sumsq += v * v;
    }
    float mu  = sum * (1.f / Bdim);
    float var = fmaxf(sumsq * (1.f / Bdim) - mu * mu, 0.f);
    float sc  = bn_g[f] / sqrtf(var + 1e-5f);
    scale[f] = sc;
    shift[f] = bn_b[f] - mu * sc;
}

__global__ __launch_bounds__(256) void xn_kernel(
    const float* __restrict__ x, const float* __restrict__ scale,
    const float* __restrict__ shift, float* __restrict__ xn)
{
    int idx = blockIdx.x * 256 + threadIdx.x;
    int f = idx % CLn;
    xn[idx] = fmaf(x[idx], scale[f], shift[f]);
}

// ---------------------------------------------------------------------------
// fp32 -> bf16 weight conversion (all 6 weight matrices, one launch)
// layout in dst: w1b8 | w1b4 | w1b2 | w2b8 | w2b4 | w2b2
// ---------------------------------------------------------------------------
__global__ __launch_bounds__(256) void convert_weights_kernel(
    const float* __restrict__ w1_8, const float* __restrict__ w1_4,
    const float* __restrict__ w1_2, const float* __restrict__ w2_8,
    const float* __restrict__ w2_4, const float* __restrict__ w2_2,
    ushort_t* __restrict__ dst)
{
    int idx = blockIdx.x * 256 + threadIdx.x;   // < 4063232 exact
    const float* src; int off;
    if      (idx < 131072)  { src = w1_8; off = 0; }
    else if (idx < 393216)  { src = w1_4; off = 131072; }
    else if (idx < 917504)  { src = w1_2; off = 393216; }
    else if (idx < 1966080) { src = w2_8; off = 917504; }
    else if (idx < 3014656) { src = w2_4; off = 1966080; }
    else                    { src = w2_2; off = 3014656; }
    dst[idx] = f2bf(src[idx - off]);
}

// ---------------------------------------------------------------------------
// Depthwise conv, stride S, kernel 2S, pad S/2; fp32 in, bf16 out
// ---------------------------------------------------------------------------
template<int S>
__global__ __launch_bounds__(256) void dwconv_kernel(
    const float* __restrict__ xn, const float* __restrict__ cw,
    ushort_t* __restrict__ outp)
{
    const int Ls = Ldim / S;
    int idx = blockIdx.x * 256 + threadIdx.x;
    if (idx >= BC * Ls) return;
    int o = idx % Ls;
    int r = idx / Ls;
    int c = r % Cdim;
    const float* xrow = xn + (size_t)r * Ldim;
    const float* w = cw + c * (2 * S);
    int start = o * S - S / 2;
    float acc = 0.f;
#pragma unroll
    for (int k = 0; k < 2 * S; ++k) {
        int pos = start + k;
        float v = (pos >= 0 && pos < Ldim) ? xrow[pos] : 0.f;
        acc = fmaf(v, w[k], acc);
    }
    outp[idx] = f2bf(acc);
}

// ---------------------------------------------------------------------------
// EMA along time (reference fp32-underflow semantics; see round-0 notes).
// One wave per row; segmented affine-scan across 64 lanes.
// ---------------------------------------------------------------------------
template<int SEG, typename T>
__global__ __launch_bounds__(64) void ema_kernel(
    const T* __restrict__ X, const float* __restrict__ al,
    T* __restrict__ Tout)
{
    const int Ls = SEG * 64;
    int row  = blockIdx.x;
    int c    = row % Cdim;
    int lane = threadIdx.x;
    float a = (float)(1.0 / (1.0 + exp(-(double)al[c])));
    float m = 1.f - a;
    const T* xr = X + (size_t)row * Ls;
    float xs[SEG];
#pragma unroll
    for (int i = 0; i < SEG; ++i) xs[i] = ldf(xr, lane * SEG + i);

    float p = 0.f;
#pragma unroll
    for (int i = 0; i < SEG; ++i) {
        float bi = a * xs[i];
        if (lane == 0 && i == 0) bi = xs[0];
        p = fmaf(m, p, bi);
    }
    float Sm = powf(m, (float)SEG);
    float Sp = p;
#pragma unroll
    for (int d = 1; d < 64; d <<= 1) {
        float pm = __shfl_up(Sp, d);
        float mm = __shfl_up(Sm, d);
        if (lane >= d) { Sp = fmaf(Sm, pm, Sp); Sm = Sm * mm; }
    }
    float carry = __shfl_up(Sp, 1);
    if (lane == 0) carry = 0.f;

    double log2m = log2((double)m);
    float y  = carry;
    float mp = powf(m, (float)(lane * SEG + 1));
    T* tr = Tout + (size_t)row * Ls;
#pragma unroll
    for (int i = 0; i < SEG; ++i) {
        int t = lane * SEG + i;
        float bi = a * xs[i];
        if (lane == 0 && i == 0) bi = xs[0];
        y = fmaf(m, y, bi);
        float dt = (1.f - mp) / a;
        mp *= m;
        double arg = (double)(Ls - 1 - t) * log2m + log2((double)dt)
                     + 39.863137138648355;   // -log2(1e-12)
        float ramp = (arg >= 0.0) ? 1.f : exp2f((float)arg);
        stf(tr, t, (y / dt) * ramp);
    }
}

// ---------------------------------------------------------------------------
// GEMM1 batched over 3 scales (blockIdx.z): H_s = bf16(gelu(D_s @ W1_s^T + b1))
// 128x128 tile, 4 waves x (64x64), BK=64, 16x16x32 MFMA, rotate-swizzled LDS.
// ---------------------------------------------------------------------------
__global__ __launch_bounds__(256) void gemm1_kernel(
    const ushort_t* __restrict__ Abase,   // A8 | A4 | A2 contiguous
    const ushort_t* __restrict__ Wbase,   // w1b8 | w1b4 | w1b2 contiguous
    const float* __restrict__ b1_8, const float* __restrict__ b1_4,
    const float* __restrict__ b1_2, ushort_t* __restrict__ Hbase)
{
    int z = blockIdx.z;
    int K = 128 << z;
    const ushort_t* A  = Abase + (size_t)2 * BC * 128 * ((1 << z) - 1);
    const ushort_t* Bw = Wbase + (size_t)131072 * ((1 << z) - 1);
    const float* bias  = (z == 0) ? b1_8 : (z == 1) ? b1_4 : b1_2;
    ushort_t* Hout     = Hbase + (size_t)z * 2 * TOT;

    __shared__ ushort_t As[128 * 64];
    __shared__ ushort_t Bs[128 * 64];
    int tid  = threadIdx.x;
    int wave = tid >> 6;
    int lane = tid & 63;
    int m0 = blockIdx.y * 128, n0 = blockIdx.x * 128;
    int wm = (wave & 1) * 64, wn = (wave >> 1) * 64;
    int lrow = lane >> 3;
    int pc   = lane & 7;
    int fr   = lane & 15;
    int quad = lane >> 4;

    f32x4 acc[4][4];
#pragma unroll
    for (int i = 0; i < 4; ++i)
#pragma unroll
        for (int j = 0; j < 4; ++j) acc[i][j] = (f32x4){0.f, 0.f, 0.f, 0.f};

    for (int k0 = 0; k0 < K; k0 += 64) {
        __syncthreads();
#pragma unroll
        for (int i = 0; i < 4; ++i) {
            int rb  = wave * 32 + i * 8;
            int row = rb + lrow;
            int lc  = (pc - row) & 7;
            async16(A  + (size_t)(m0 + row) * K + k0 + lc * 8, &As[rb * 64]);
            async16(Bw + (size_t)(n0 + row) * K + k0 + lc * 8, &Bs[rb * 64]);
        }
        __syncthreads();
#pragma unroll
        for (int kk = 0; kk < 64; kk += 32) {
            s16x8 af[4], bfr[4];
            int lcA = (kk >> 3) + quad;
#pragma unroll
            for (int t = 0; t < 4; ++t) {
                int mr  = wm + t * 16 + fr;
                af[t]  = *(const s16x8*)&As[mr * 64 + ((lcA + mr) & 7) * 8];
                int nr  = wn + t * 16 + fr;
                bfr[t] = *(const s16x8*)&Bs[nr * 64 + ((lcA + nr) & 7) * 8];
            }
#pragma unroll
            for (int mt = 0; mt < 4; ++mt)
#pragma unroll
                for (int nt = 0; nt < 4; ++nt)
                    acc[mt][nt] = __builtin_amdgcn_mfma_f32_16x16x32_bf16(
                        af[mt], bfr[nt], acc[mt][nt], 0, 0, 0);
        }
    }
    // D layout: m = quad*4 + reg, n = lane&15
#pragma unroll
    for (int mt = 0; mt < 4; ++mt)
#pragma unroll
        for (int nt = 0; nt < 4; ++nt) {
            int col = n0 + wn + nt * 16 + fr;
#pragma unroll
            for (int r = 0; r < 4; ++r) {
                size_t row = m0 + wm + mt * 16 + quad * 4 + r;
                float zv = acc[mt][nt][r] + bias[col];
                zv = 0.5f * zv * (1.f + erff(zv * 0.70710678118654752f));
                Hout[row * 1024 + col] = f2bf(zv);
            }
        }
}

// ---------------------------------------------------------------------------
// GEMM2 (K=3072 scale-concat, per-scale gate fold):
//   accF = sum_s g_s * (H_side_s @ W2_s^T),  side = trend (IS_U=0) / up (IS_U=1)
//   IS_U=0: trend[idx]  = accF + cb2[col] + g1*t1[idx]
//   IS_U=1: season[idx] = accF + cb2[col] + g1*xn[idx] - trend[idx]
//   (cb2 = sum_s g_s*b2_s; t1 cancels in season algebraically)
// ---------------------------------------------------------------------------
template<int IS_U>
__global__ __launch_bounds__(256) void gemm2_kernel(
    const ushort_t* __restrict__ Hbase,   // H8 | H4 | H2, each [up|trend] 2*TOT
    const ushort_t* __restrict__ W2base,  // w2b8 | w2b4 | w2b2 contiguous
    const float* __restrict__ b2_8, const float* __restrict__ b2_4,
    const float* __restrict__ b2_2, const float* __restrict__ g,
    const float* __restrict__ aux,        // t1 (IS_U=0) or xn (IS_U=1)
    const float* __restrict__ trend_in,   // IS_U=1 only
    float* __restrict__ outp)             // trend half or season half
{
    __shared__ ushort_t As[128 * 64];
    __shared__ ushort_t Bs[128 * 64];
    int tid  = threadIdx.x;
    int wave = tid >> 6;
    int lane = tid & 63;
    int m0 = blockIdx.y * 128, n0 = blockIdx.x * 128;   // M = 8192 rows
    int wm = (wave & 1) * 64, wn = (wave >> 1) * 64;
    int lrow = lane >> 3;
    int pc   = lane & 7;
    int fr   = lane & 15;
    int quad = lane >> 4;
    int b = m0 >> 7;
    float gv0 = g[b * 4 + 0], gv1 = g[b * 4 + 1], gv2 = g[b * 4 + 2];
    float g1  = g[b * 4 + 3];

    f32x4 accF[4][4], accP[4][4];
#pragma unroll
    for (int i = 0; i < 4; ++i)
#pragma unroll
        for (int j = 0; j < 4; ++j) {
            accF[i][j] = (f32x4){0.f, 0.f, 0.f, 0.f};
            accP[i][j] = (f32x4){0.f, 0.f, 0.f, 0.f};
        }

    for (int s = 0; s < 3; ++s) {
        const ushort_t* A  = Hbase + (size_t)s * 2 * TOT + (IS_U ? 0 : TOT);
        const ushort_t* Bw = W2base + (size_t)s * 1048576;
        for (int k0 = 0; k0 < 1024; k0 += 64) {
            __syncthreads();
#pragma unroll
            for (int i = 0; i < 4; ++i) {
                int rb  = wave * 32 + i * 8;
                int row = rb + lrow;
                int lc  = (pc - row) & 7;
                async16(A  + (size_t)(m0 + row) * 1024 + k0 + lc * 8, &As[rb * 64]);
                async16(Bw + (size_t)(n0 + row) * 1024 + k0 + lc * 8, &Bs[rb * 64]);
            }
            __syncthreads();
#pragma unroll
            for (int kk = 0; kk < 64; kk += 32) {
                s16x8 af[4], bfr[4];
                int lcA = (kk >> 3) + quad;
#pragma unroll
                for (int t = 0; t < 4; ++t) {
                    int mr  = wm + t * 16 + fr;
                    af[t]  = *(const s16x8*)&As[mr * 64 + ((lcA + mr) & 7) * 8];
                    int nr  = wn + t * 16 + fr;
                    bfr[t] = *(const s16x8*)&Bs[nr * 64 + ((lcA + nr) & 7) * 8];
                }
#pragma unroll
                for (int mt = 0; mt < 4; ++mt)
#pragma unroll
                    for (int nt = 0; nt < 4; ++nt)
                        accP[mt][nt] = __builtin_amdgcn_mfma_f32_16x16x32_bf16(
                            af[mt], bfr[nt], accP[mt][nt], 0, 0, 0);
            }
        }
        float gs = (s == 0) ? gv0 : (s == 1) ? gv1 : gv2;
#pragma unroll
        for (int mt = 0; mt < 4; ++mt)
#pragma unroll
            for (int nt = 0; nt < 4; ++nt) {
#pragma unroll
                for (int r = 0; r < 4; ++r)
                    accF[mt][nt][r] = fmaf(gs, accP[mt][nt][r], accF[mt][nt][r]);
                accP[mt][nt] = (f32x4){0.f, 0.f, 0.f, 0.f};
            }
    }

    // epilogue — D layout: m = quad*4 + reg, n = lane&15
#pragma unroll
    for (int mt = 0; mt < 4; ++mt)
#pragma unroll
        for (int nt = 0; nt < 4; ++nt) {
            int col = n0 + wn + nt * 16 + fr;
            float cb2 = gv0 * b2_8[col] + gv1 * b2_4[col] + gv2 * b2_2[col];
#pragma unroll
            for (int r = 0; r < 4; ++r) {
                size_t row = m0 + wm + mt * 16 + quad * 4 + r;
                size_t idx = row * 1024 + col;
                float v = accF[mt][nt][r] + cb2;
                if (IS_U) v += g1 * aux[idx] - trend_in[idx];   // season
                else      v += g1 * aux[idx];                    // trend
                outp[idx] = v;
            }
        }
}

// ---------------------------------------------------------------------------
// column sums of the three W2 matrices (gate matvec trick), 4-way l-split
// grid (16, 3): 64 cols x 4 l-strips per block
// ---------------------------------------------------------------------------
__global__ __launch_bounds__(256) void w2colsum_kernel(
    const float* __restrict__ w2_8, const float* __restrict__ w2_4,
    const float* __restrict__ w2_2, float* __restrict__ w2cs)
{
    const float* w = (blockIdx.y == 0) ? w2_8 : (blockIdx.y == 1) ? w2_4 : w2_2;
    int h  = blockIdx.x * 64 + (threadIdx.x & 63);
    int ls = threadIdx.x >> 6;
    float s = 0.f;
    for (int l = ls; l < 1024; l += 4) s += w[(size_t)l * 1024 + h];
    __shared__ float red[4][64];
    red[ls][threadIdx.x & 63] = s;
    __syncthreads();
    if (ls == 0)
        w2cs[blockIdx.y * 1024 + h] =
            red[0][threadIdx.x] + red[1][threadIdx.x] +
            red[2][threadIdx.x] + red[3][threadIdx.x];
}

// season row-sum via H matvec, batched over 3 scales (blockIdx.y)
__global__ __launch_bounds__(256) void rowsum_h_kernel(
    const ushort_t* __restrict__ Hbase, const float* __restrict__ w2cs,
    float* __restrict__ rs)
{
    int r = blockIdx.x, z = blockIdx.y, tid = threadIdx.x;
    const ushort_t* hu = Hbase + (size_t)z * 2 * TOT + (size_t)r * 1024;
    const ushort_t* ht = hu + (size_t)BC * 1024;
    const float* cs = w2cs + z * 1024;
    float s = 0.f;
    for (int h = tid; h < 1024; h += 256)
        s += (bf2f(hu[h]) - bf2f(ht[h])) * cs[h];
#pragma unroll
    for (int d = 32; d > 0; d >>= 1) s += __shfl_down(s, d);
    __shared__ float red[4];
    if ((tid & 63) == 0) red[tid >> 6] = s;
    __syncthreads();
    if (tid == 0) rs[(size_t)z * BC + r] = red[0] + red[1] + red[2] + red[3];
}

// season row-sum for scale 1: sum_l (xn - t1)
__global__ __launch_bounds__(256) void rowdiff_sum_kernel(
    const float* __restrict__ Up, const float* __restrict__ Tp,
    float* __restrict__ rs)
{
    int r = blockIdx.x, tid = threadIdx.x;
    const float* ur = Up + (size_t)r * Ldim;
    const float* tr = Tp + (size_t)r * Ldim;
    float s = 0.f;
    for (int l = tid; l < Ldim; l += 256) s += ur[l] - tr[l];
#pragma unroll
    for (int d = 32; d > 0; d >>= 1) s += __shfl_down(s, d);
    __shared__ float red[4];
    if ((tid & 63) == 0) red[tid >> 6] = s;
    __syncthreads();
    if (tid == 0) rs[r] = red[0] + red[1] + red[2] + red[3];
}

// ---------------------------------------------------------------------------
// gates: sigmoid(mean_L(season) . gw + gb) per scale, then normalize over 4
// ---------------------------------------------------------------------------
__global__ __launch_bounds__(128) void gate_kernel(
    const float* __restrict__ rs,
    const float* __restrict__ gw8, const float* __restrict__ gb8,
    const float* __restrict__ gw4, const float* __restrict__ gb4,
    const float* __restrict__ gw2, const float* __restrict__ gb2,
    const float* __restrict__ gw1, const float* __restrict__ gb1,
    float* __restrict__ g)
{
    int b = blockIdx.x;
    int c = threadIdx.x;
    const float* gws[4] = {gw8, gw4, gw2, gw1};
    const float* gbs[4] = {gb8, gb4, gb2, gb1};
    __shared__ float buf[128];
    __shared__ float gates[4];
    for (int si = 0; si < 4; ++si) {
        buf[c] = rs[si * BC + b * Cdim + c] * (1.f / Ldim) * gws[si][c];
        __syncthreads();
        for (int off = 64; off >= 1; off >>= 1) {
            if (c < off) buf[c] += buf[c + off];
            __syncthreads();
        }
        if (c == 0) {
            float z = buf[0] + gbs[si][0];
            gates[si] = 1.f / (1.f + expf(-z));
        }
        __syncthreads();
    }
    if (c == 0) {
        float s = gates[0] + gates[1] + gates[2] + gates[3] + 1e-6f;
#pragma unroll
        for (int si = 0; si < 4; ++si) g[b * 4 + si] = gates[si] / s;
    }
}

// ---------------------------------------------------------------------------
extern "C" void kernel_launch(void* const* d_in, const int* in_sizes, int n_in,
                              void* d_out, int out_size, void* d_ws, size_t ws_size,
                              hipStream_t stream)
{
    const float* x    = (const float*)d_in[0];
    const float* bn_g = (const float*)d_in[1];
    const float* bn_b = (const float*)d_in[2];
    const float* cw8  = (const float*)d_in[3];
    const float* w1_8 = (const float*)d_in[4];
    const float* b1_8 = (const float*)d_in[5];
    const float* w2_8 = (const float*)d_in[6];
    const float* b2_8 = (const float*)d_in[7];
    const float* cw4  = (const float*)d_in[8];
    const float* w1_4 = (const float*)d_in[9];
    const float* b1_4 = (const float*)d_in[10];
    const float* w2_4 = (const float*)d_in[11];
    const float* b2_4 = (const float*)d_in[12];
    const float* cw2  = (const float*)d_in[13];
    const float* w1_2 = (const float*)d_in[14];
    const float* b1_2 = (const float*)d_in[15];
    const float* w2_2 = (const float*)d_in[16];
    const float* b2_2 = (const float*)d_in[17];
    const float* gw8  = (const float*)d_in[18];
    const float* gb8  = (const float*)d_in[19];
    const float* al8  = (const float*)d_in[20];
    const float* gw4  = (const float*)d_in[21];
    const float* gb4  = (const float*)d_in[22];
    const float* al4  = (const float*)d_in[23];
    const float* gw2  = (const float*)d_in[24];
    const float* gb2  = (const float*)d_in[25];
    const float* al2  = (const float*)d_in[26];
    const float* gw1  = (const float*)d_in[27];
    const float* gb1  = (const float*)d_in[28];
    const float* al1  = (const float*)d_in[29];

    // workspace (~172 MB)
    float*    p_xn  = (float*)d_ws;                    // TOT
    float*    p_t1  = p_xn + TOT;                      // TOT
    ushort_t* p_H8  = (ushort_t*)(p_t1 + TOT);         // 3 x 2*TOT bf16 (H8|H4|H2)
    ushort_t* p_wb  = p_H8 + 6 * (size_t)TOT;          // 4063232 bf16 weights
    ushort_t* p_w1b = p_wb;                            // w1b8|w1b4|w1b2
    ushort_t* p_w2b = p_wb + 917504;                   // w2b8|w2b4|w2b2
    float*    p_sc  = (float*)(p_wb + 4063232);        // CLn
    float*    p_sh  = p_sc + CLn;                      // CLn
    float*    p_w2cs = p_sh + CLn;                     // 3*1024
    float*    p_rs  = p_w2cs + 3 * 1024;               // 4*BC
    float*    p_g   = p_rs + 4 * BC;                   // 256
    // A-tiles (bf16 down|trend per scale) aliased into d_out season half
    // (28 MB < 33.5 MB; dead after GEMM1; trend half untouched)
    ushort_t* p_A8 = (ushort_t*)d_out;                 // 2*BC*128
    ushort_t* p_A4 = p_A8 + 2 * (size_t)BC * 128;      // 2*BC*256
    ushort_t* p_A2 = p_A4 + 2 * (size_t)BC * 256;      // 2*BC*512
    float*    p_season = (float*)d_out;
    float*    p_trend  = (float*)d_out + TOT;

    bn_stats_kernel<<<CLn / 256, 256, 0, stream>>>(x, bn_g, bn_b, p_sc, p_sh);
    xn_kernel<<<TOT / 256, 256, 0, stream>>>(x, p_sc, p_sh, p_xn);
    ema_kernel<16, float><<<BC, 64, 0, stream>>>(p_xn, al1, p_t1);
    convert_weights_kernel<<<4063232 / 256, 256, 0, stream>>>(
        w1_8, w1_4, w1_2, w2_8, w2_4, w2_2, p_wb);
    w2colsum_kernel<<<dim3(16, 3), 256, 0, stream>>>(w2_8, w2_4, w2_2, p_w2cs);

    dwconv_kernel<8><<<BC * 128 / 256, 256, 0, stream>>>(p_xn, cw8, p_A8);
    dwconv_kernel<4><<<BC * 256 / 256, 256, 0, stream>>>(p_xn, cw4, p_A4);
    dwconv_kernel<2><<<BC * 512 / 256, 256, 0, stream>>>(p_xn, cw2, p_A2);
    ema_kernel<2, ushort_t><<<BC, 64, 0, stream>>>(p_A8, al8, p_A8 + (size_t)BC * 128);
    ema_kernel<4, ushort_t><<<BC, 64, 0, stream>>>(p_A4, al4, p_A4 + (size_t)BC * 256);
    ema_kernel<8, ushort_t><<<BC, 64, 0, stream>>>(p_A2, al2, p_A2 + (size_t)BC * 512);

    // batched GEMM1: H_s = gelu(D_s @ W1_s^T + b1_s)
    gemm1_kernel<<<dim3(8, 128, 3), 256, 0, stream>>>(
        p_A8, p_w1b, b1_8, b1_4, b1_2, p_H8);

    // gates
    rowsum_h_kernel<<<dim3(BC, 3), 256, 0, stream>>>(p_H8, p_w2cs, p_rs);
    rowdiff_sum_kernel<<<BC, 256, 0, stream>>>(p_xn, p_t1, p_rs + 3 * BC);
    gate_kernel<<<Bdim, 128, 0, stream>>>(p_rs, gw8, gb8, gw4, gb4,
                                          gw2, gb2, gw1, gb1, p_g);

    // fused write-only output GEMMs (K=3072): trend first, then season
    dim3 g2(8, 64);   // N=1024/128, M=8192/128
    gemm2_kernel<0><<<g2, 256, 0, stream>>>(p_H8, p_w2b, b2_8, b2_4, b2_2,
                                            p_g, p_t1, nullptr, p_trend);
    gemm2_kernel<1><<<g2, 256, 0, stream>>>(p_H8, p_w2b, b2_8, b2_4, b2_2,
                                            p_g, p_xn, p_trend, p_season);
}

// Round 5
// 638.808 us; speedup vs baseline: 3.3653x; 1.1666x over previous
//
#include <hip/hip_runtime.h>
#include <hip/hip_bf16.h>
#include <math.h>

// Problem constants
#define Bdim 64
#define Cdim 128
#define Ldim 1024
#define BC   (Bdim * Cdim)      // 8192 rows
#define CLn  (Cdim * Ldim)      // 131072 features
#define TOT  (Bdim * CLn)       // 8388608 elements per (B,C,L) tensor

typedef unsigned short ushort_t;
typedef short s16x8 __attribute__((ext_vector_type(8)));   // 8 bf16 (4 VGPRs)
typedef float f32x4 __attribute__((ext_vector_type(4)));

__device__ __forceinline__ float bf2f(ushort_t u) {
    return __uint_as_float(((unsigned)u) << 16);
}
__device__ __forceinline__ ushort_t f2bf(float f) {
    __hip_bfloat16 h = __float2bfloat16(f);
    return *(ushort_t*)&h;
}
// async global->LDS, 16B per lane; lds base wave-uniform, lane i -> base+i*16B
__device__ __forceinline__ void async16(const ushort_t* g, ushort_t* l) {
    __builtin_amdgcn_global_load_lds(
        (const __attribute__((address_space(1))) unsigned int*)g,
        (__attribute__((address_space(3))) unsigned int*)l, 16, 0, 0);
}

__device__ __forceinline__ float ldf(const float* p, size_t i) { return p[i]; }
__device__ __forceinline__ float ldf(const ushort_t* p, size_t i) { return bf2f(p[i]); }
__device__ __forceinline__ void stf(float* p, size_t i, float v) { p[i] = v; }
__device__ __forceinline__ void stf(ushort_t* p, size_t i, float v) { p[i] = f2bf(v); }

// ---------------------------------------------------------------------------
// BN: per-feature mean/var over batch axis -> fused scale/shift
// ---------------------------------------------------------------------------
__global__ __launch_bounds__(256) void bn_stats_kernel(
    const float* __restrict__ x, const float* __restrict__ bn_g,
    const float* __restrict__ bn_b, float* __restrict__ scale,
    float* __restrict__ shift)
{
    int f = blockIdx.x * 256 + threadIdx.x;
    float sum = 0.f, sumsq = 0.f;
    for (int b = 0; b < Bdim; ++b) {
        float v = x[(size_t)b * CLn + f];
        sum += v; sumsq += v * v;
    }
    float mu  = sum * (1.f / Bdim);
    float var = fmaxf(sumsq * (1.f / Bdim) - mu * mu, 0.f);
    float sc  = bn_g[f] / sqrtf(var + 1e-5f);
    scale[f] = sc;
    shift[f] = bn_b[f] - mu * sc;
}

__global__ __launch_bounds__(256) void xn_kernel(
    const float* __restrict__ x, const float* __restrict__ scale,
    const float* __restrict__ shift, float* __restrict__ xn)
{
    int idx = blockIdx.x * 256 + threadIdx.x;
    int f = idx % CLn;
    xn[idx] = fmaf(x[idx], scale[f], shift[f]);
}

// ---------------------------------------------------------------------------
// fp32 -> bf16 weight conversion (all 6 weight matrices, one launch)
// layout in dst: w1b8 | w1b4 | w1b2 | w2b8 | w2b4 | w2b2
// ---------------------------------------------------------------------------
__global__ __launch_bounds__(256) void convert_weights_kernel(
    const float* __restrict__ w1_8, const float* __restrict__ w1_4,
    const float* __restrict__ w1_2, const float* __restrict__ w2_8,
    const float* __restrict__ w2_4, const float* __restrict__ w2_2,
    ushort_t* __restrict__ dst)
{
    int idx = blockIdx.x * 256 + threadIdx.x;   // < 4063232 exact
    const float* src; int off;
    if      (idx < 131072)  { src = w1_8; off = 0; }
    else if (idx < 393216)  { src = w1_4; off = 131072; }
    else if (idx < 917504)  { src = w1_2; off = 393216; }
    else if (idx < 1966080) { src = w2_8; off = 917504; }
    else if (idx < 3014656) { src = w2_4; off = 1966080; }
    else                    { src = w2_2; off = 3014656; }
    dst[idx] = f2bf(src[idx - off]);
}

// ---------------------------------------------------------------------------
// Depthwise conv, stride S, kernel 2S, pad S/2; fp32 in, bf16 out
// ---------------------------------------------------------------------------
template<int S>
__global__ __launch_bounds__(256) void dwconv_kernel(
    const float* __restrict__ xn, const float* __restrict__ cw,
    ushort_t* __restrict__ outp)
{
    const int Ls = Ldim / S;
    int idx = blockIdx.x * 256 + threadIdx.x;
    if (idx >= BC * Ls) return;
    int o = idx % Ls;
    int r = idx / Ls;
    int c = r % Cdim;
    const float* xrow = xn + (size_t)r * Ldim;
    const float* w = cw + c * (2 * S);
    int start = o * S - S / 2;
    float acc = 0.f;
#pragma unroll
    for (int k = 0; k < 2 * S; ++k) {
        int pos = start + k;
        float v = (pos >= 0 && pos < Ldim) ? xrow[pos] : 0.f;
        acc = fmaf(v, w[k], acc);
    }
    outp[idx] = f2bf(acc);
}

// ---------------------------------------------------------------------------
// EMA along time (reference fp32-underflow semantics; see round-0 notes).
// One wave per row; segmented affine-scan across 64 lanes.
// ---------------------------------------------------------------------------
template<int SEG, typename T>
__global__ __launch_bounds__(64) void ema_kernel(
    const T* __restrict__ X, const float* __restrict__ al,
    T* __restrict__ Tout)
{
    const int Ls = SEG * 64;
    int row  = blockIdx.x;
    int c    = row % Cdim;
    int lane = threadIdx.x;
    float a = (float)(1.0 / (1.0 + exp(-(double)al[c])));
    float m = 1.f - a;
    const T* xr = X + (size_t)row * Ls;
    float xs[SEG];
#pragma unroll
    for (int i = 0; i < SEG; ++i) xs[i] = ldf(xr, lane * SEG + i);

    float p = 0.f;
#pragma unroll
    for (int i = 0; i < SEG; ++i) {
        float bi = a * xs[i];
        if (lane == 0 && i == 0) bi = xs[0];
        p = fmaf(m, p, bi);
    }
    float Sm = powf(m, (float)SEG);
    float Sp = p;
#pragma unroll
    for (int d = 1; d < 64; d <<= 1) {
        float pm = __shfl_up(Sp, d);
        float mm = __shfl_up(Sm, d);
        if (lane >= d) { Sp = fmaf(Sm, pm, Sp); Sm = Sm * mm; }
    }
    float carry = __shfl_up(Sp, 1);
    if (lane == 0) carry = 0.f;

    double log2m = log2((double)m);
    float y  = carry;
    float mp = powf(m, (float)(lane * SEG + 1));
    T* tr = Tout + (size_t)row * Ls;
#pragma unroll
    for (int i = 0; i < SEG; ++i) {
        int t = lane * SEG + i;
        float bi = a * xs[i];
        if (lane == 0 && i == 0) bi = xs[0];
        y = fmaf(m, y, bi);
        float dt = (1.f - mp) / a;
        mp *= m;
        double arg = (double)(Ls - 1 - t) * log2m + log2((double)dt)
                     + 39.863137138648355;   // -log2(1e-12)
        float ramp = (arg >= 0.0) ? 1.f : exp2f((float)arg);
        stf(tr, t, (y / dt) * ramp);
    }
}

// ---------------------------------------------------------------------------
// GEMM1 batched over 3 scales (blockIdx.z): H_s = bf16(gelu(D_s @ W1_s^T + b1))
// grid (128, 8, 3): x = M-tile (fast) so blocks sharing an A-tile land on the
// same XCD (ids differ by multiples of 128 ≡ 0 mod 8) -> A-tile L2 reuse.
// ---------------------------------------------------------------------------
__global__ __launch_bounds__(256) void gemm1_kernel(
    const ushort_t* __restrict__ Abase,   // A8 | A4 | A2 contiguous
    const ushort_t* __restrict__ Wbase,   // w1b8 | w1b4 | w1b2 contiguous
    const float* __restrict__ b1_8, const float* __restrict__ b1_4,
    const float* __restrict__ b1_2, ushort_t* __restrict__ Hbase)
{
    int z = blockIdx.z;
    int K = 128 << z;
    const ushort_t* A  = Abase + (size_t)2 * BC * 128 * ((1 << z) - 1);
    const ushort_t* Bw = Wbase + (size_t)131072 * ((1 << z) - 1);
    const float* bias  = (z == 0) ? b1_8 : (z == 1) ? b1_4 : b1_2;
    ushort_t* Hout     = Hbase + (size_t)z * 2 * TOT;

    __shared__ ushort_t As[128 * 64];
    __shared__ ushort_t Bs[128 * 64];
    int tid  = threadIdx.x;
    int wave = tid >> 6;
    int lane = tid & 63;
    int m0 = blockIdx.x * 128, n0 = blockIdx.y * 128;
    int wm = (wave & 1) * 64, wn = (wave >> 1) * 64;
    int lrow = lane >> 3;
    int pc   = lane & 7;
    int fr   = lane & 15;
    int quad = lane >> 4;

    f32x4 acc[4][4];
#pragma unroll
    for (int i = 0; i < 4; ++i)
#pragma unroll
        for (int j = 0; j < 4; ++j) acc[i][j] = (f32x4){0.f, 0.f, 0.f, 0.f};

    for (int k0 = 0; k0 < K; k0 += 64) {
        __syncthreads();
#pragma unroll
        for (int i = 0; i < 4; ++i) {
            int rb  = wave * 32 + i * 8;
            int row = rb + lrow;
            int lc  = (pc - row) & 7;
            async16(A  + (size_t)(m0 + row) * K + k0 + lc * 8, &As[rb * 64]);
            async16(Bw + (size_t)(n0 + row) * K + k0 + lc * 8, &Bs[rb * 64]);
        }
        __syncthreads();
#pragma unroll
        for (int kk = 0; kk < 64; kk += 32) {
            s16x8 af[4], bfr[4];
            int lcA = (kk >> 3) + quad;
#pragma unroll
            for (int t = 0; t < 4; ++t) {
                int mr  = wm + t * 16 + fr;
                af[t]  = *(const s16x8*)&As[mr * 64 + ((lcA + mr) & 7) * 8];
                int nr  = wn + t * 16 + fr;
                bfr[t] = *(const s16x8*)&Bs[nr * 64 + ((lcA + nr) & 7) * 8];
            }
#pragma unroll
            for (int mt = 0; mt < 4; ++mt)
#pragma unroll
                for (int nt = 0; nt < 4; ++nt)
                    acc[mt][nt] = __builtin_amdgcn_mfma_f32_16x16x32_bf16(
                        af[mt], bfr[nt], acc[mt][nt], 0, 0, 0);
        }
    }
    // D layout: m = quad*4 + reg, n = lane&15
#pragma unroll
    for (int mt = 0; mt < 4; ++mt)
#pragma unroll
        for (int nt = 0; nt < 4; ++nt) {
            int col = n0 + wn + nt * 16 + fr;
#pragma unroll
            for (int r = 0; r < 4; ++r) {
                size_t row = m0 + wm + mt * 16 + quad * 4 + r;
                float zv = acc[mt][nt][r] + bias[col];
                zv = 0.5f * zv * (1.f + erff(zv * 0.70710678118654752f));
                Hout[row * 1024 + col] = f2bf(zv);
            }
        }
}

// ---------------------------------------------------------------------------
// GEMM2 (K=3072 scale-concat, SINGLE-accumulator gate fold via ratio rescale):
//   sum_s g_s A_sB_s = g2*(A2B2 + (g1/g2)*(A1B1 + (g0/g1)*A0B0))
//   IS_U=0: trend[idx]  = acc + cb2[col] + g1*t1[idx]
//   IS_U=1: season[idx] = acc + cb2[col] + g1*xn[idx] - trend[idx]
// grid (64, 8): x = M-tile (fast) for XCD-local A-tile L2 reuse.
// ---------------------------------------------------------------------------
template<int IS_U>
__global__ __launch_bounds__(256) void gemm2_kernel(
    const ushort_t* __restrict__ Hbase,   // H8 | H4 | H2, each [up|trend] 2*TOT
    const ushort_t* __restrict__ W2base,  // w2b8 | w2b4 | w2b2 contiguous
    const float* __restrict__ b2_8, const float* __restrict__ b2_4,
    const float* __restrict__ b2_2, const float* __restrict__ g,
    const float* __restrict__ aux,        // t1 (IS_U=0) or xn (IS_U=1)
    const float* __restrict__ trend_in,   // IS_U=1 only
    float* __restrict__ outp)             // trend half or season half
{
    __shared__ ushort_t As[128 * 64];
    __shared__ ushort_t Bs[128 * 64];
    int tid  = threadIdx.x;
    int wave = tid >> 6;
    int lane = tid & 63;
    int m0 = blockIdx.x * 128, n0 = blockIdx.y * 128;   // M = 8192 rows
    int wm = (wave & 1) * 64, wn = (wave >> 1) * 64;
    int lrow = lane >> 3;
    int pc   = lane & 7;
    int fr   = lane & 15;
    int quad = lane >> 4;
    int b = m0 >> 7;                       // 128 rows = one batch
    float gv0 = g[b * 4 + 0], gv1 = g[b * 4 + 1], gv2 = g[b * 4 + 2];
    float g1  = g[b * 4 + 3];
    float gsv[3] = {gv0, gv1, gv2};

    f32x4 acc[4][4];
#pragma unroll
    for (int i = 0; i < 4; ++i)
#pragma unroll
        for (int j = 0; j < 4; ++j) acc[i][j] = (f32x4){0.f, 0.f, 0.f, 0.f};

    for (int s = 0; s < 3; ++s) {
        if (s > 0) {
            float r = gsv[s - 1] / fmaxf(gsv[s], 1e-30f);
#pragma unroll
            for (int mt = 0; mt < 4; ++mt)
#pragma unroll
                for (int nt = 0; nt < 4; ++nt)
#pragma unroll
                    for (int rr = 0; rr < 4; ++rr)
                        acc[mt][nt][rr] *= r;
        }
        const ushort_t* A  = Hbase + (size_t)s * 2 * TOT + (IS_U ? 0 : TOT);
        const ushort_t* Bw = W2base + (size_t)s * 1048576;
        for (int k0 = 0; k0 < 1024; k0 += 64) {
            __syncthreads();
#pragma unroll
            for (int i = 0; i < 4; ++i) {
                int rb  = wave * 32 + i * 8;
                int row = rb + lrow;
                int lc  = (pc - row) & 7;
                async16(A  + (size_t)(m0 + row) * 1024 + k0 + lc * 8, &As[rb * 64]);
                async16(Bw + (size_t)(n0 + row) * 1024 + k0 + lc * 8, &Bs[rb * 64]);
            }
            __syncthreads();
#pragma unroll
            for (int kk = 0; kk < 64; kk += 32) {
                s16x8 af[4], bfr[4];
                int lcA = (kk >> 3) + quad;
#pragma unroll
                for (int t = 0; t < 4; ++t) {
                    int mr  = wm + t * 16 + fr;
                    af[t]  = *(const s16x8*)&As[mr * 64 + ((lcA + mr) & 7) * 8];
                    int nr  = wn + t * 16 + fr;
                    bfr[t] = *(const s16x8*)&Bs[nr * 64 + ((lcA + nr) & 7) * 8];
                }
#pragma unroll
                for (int mt = 0; mt < 4; ++mt)
#pragma unroll
                    for (int nt = 0; nt < 4; ++nt)
                        acc[mt][nt] = __builtin_amdgcn_mfma_f32_16x16x32_bf16(
                            af[mt], bfr[nt], acc[mt][nt], 0, 0, 0);
            }
        }
    }
    // final scale by g2
#pragma unroll
    for (int mt = 0; mt < 4; ++mt)
#pragma unroll
        for (int nt = 0; nt < 4; ++nt)
#pragma unroll
            for (int rr = 0; rr < 4; ++rr)
                acc[mt][nt][rr] *= gv2;

    // epilogue — D layout: m = quad*4 + reg, n = lane&15
#pragma unroll
    for (int mt = 0; mt < 4; ++mt)
#pragma unroll
        for (int nt = 0; nt < 4; ++nt) {
            int col = n0 + wn + nt * 16 + fr;
            float cb2 = gv0 * b2_8[col] + gv1 * b2_4[col] + gv2 * b2_2[col];
#pragma unroll
            for (int r = 0; r < 4; ++r) {
                size_t row = m0 + wm + mt * 16 + quad * 4 + r;
                size_t idx = row * 1024 + col;
                float v = acc[mt][nt][r] + cb2;
                if (IS_U) v += g1 * aux[idx] - trend_in[idx];   // season
                else      v += g1 * aux[idx];                    // trend
                outp[idx] = v;
            }
        }
}

// ---------------------------------------------------------------------------
// column sums of the three W2 matrices (gate matvec trick), 4-way l-split
// ---------------------------------------------------------------------------
__global__ __launch_bounds__(256) void w2colsum_kernel(
    const float* __restrict__ w2_8, const float* __restrict__ w2_4,
    const float* __restrict__ w2_2, float* __restrict__ w2cs)
{
    const float* w = (blockIdx.y == 0) ? w2_8 : (blockIdx.y == 1) ? w2_4 : w2_2;
    int h  = blockIdx.x * 64 + (threadIdx.x & 63);
    int ls = threadIdx.x >> 6;
    float s = 0.f;
    for (int l = ls; l < 1024; l += 4) s += w[(size_t)l * 1024 + h];
    __shared__ float red[4][64];
    red[ls][threadIdx.x & 63] = s;
    __syncthreads();
    if (ls == 0)
        w2cs[blockIdx.y * 1024 + h] =
            red[0][threadIdx.x] + red[1][threadIdx.x] +
            red[2][threadIdx.x] + red[3][threadIdx.x];
}

// season row-sum via H matvec, batched over 3 scales (blockIdx.y)
__global__ __launch_bounds__(256) void rowsum_h_kernel(
    const ushort_t* __restrict__ Hbase, const float* __restrict__ w2cs,
    float* __restrict__ rs)
{
    int r = blockIdx.x, z = blockIdx.y, tid = threadIdx.x;
    const ushort_t* hu = Hbase + (size_t)z * 2 * TOT + (size_t)r * 1024;
    const ushort_t* ht = hu + (size_t)BC * 1024;
    const float* cs = w2cs + z * 1024;
    float s = 0.f;
    for (int h = tid; h < 1024; h += 256)
        s += (bf2f(hu[h]) - bf2f(ht[h])) * cs[h];
#pragma unroll
    for (int d = 32; d > 0; d >>= 1) s += __shfl_down(s, d);
    __shared__ float red[4];
    if ((tid & 63) == 0) red[tid >> 6] = s;
    __syncthreads();
    if (tid == 0) rs[(size_t)z * BC + r] = red[0] + red[1] + red[2] + red[3];
}

// season row-sum for scale 1: sum_l (xn - t1)
__global__ __launch_bounds__(256) void rowdiff_sum_kernel(
    const float* __restrict__ Up, const float* __restrict__ Tp,
    float* __restrict__ rs)
{
    int r = blockIdx.x, tid = threadIdx.x;
    const float* ur = Up + (size_t)r * Ldim;
    const float* tr = Tp + (size_t)r * Ldim;
    float s = 0.f;
    for (int l = tid; l < Ldim; l += 256) s += ur[l] - tr[l];
#pragma unroll
    for (int d = 32; d > 0; d >>= 1) s += __shfl_down(s, d);
    __shared__ float red[4];
    if ((tid & 63) == 0) red[tid >> 6] = s;
    __syncthreads();
    if (tid == 0) rs[r] = red[0] + red[1] + red[2] + red[3];
}

// ---------------------------------------------------------------------------
// gates: sigmoid(mean_L(season) . gw + gb) per scale, then normalize over 4
// ---------------------------------------------------------------------------
__global__ __launch_bounds__(128) void gate_kernel(
    const float* __restrict__ rs,
    const float* __restrict__ gw8, const float* __restrict__ gb8,
    const float* __restrict__ gw4, const float* __restrict__ gb4,
    const float* __restrict__ gw2, const float* __restrict__ gb2,
    const float* __restrict__ gw1, const float* __restrict__ gb1,
    float* __restrict__ g)
{
    int b = blockIdx.x;
    int c = threadIdx.x;
    const float* gws[4] = {gw8, gw4, gw2, gw1};
    const float* gbs[4] = {gb8, gb4, gb2, gb1};
    __shared__ float buf[128];
    __shared__ float gates[4];
    for (int si = 0; si < 4; ++si) {
        buf[c] = rs[si * BC + b * Cdim + c] * (1.f / Ldim) * gws[si][c];
        __syncthreads();
        for (int off = 64; off >= 1; off >>= 1) {
            if (c < off) buf[c] += buf[c + off];
            __syncthreads();
        }
        if (c == 0) {
            float z = buf[0] + gbs[si][0];
            gates[si] = 1.f / (1.f + expf(-z));
        }
        __syncthreads();
    }
    if (c == 0) {
        float s = gates[0] + gates[1] + gates[2] + gates[3] + 1e-6f;
#pragma unroll
        for (int si = 0; si < 4; ++si) g[b * 4 + si] = gates[si] / s;
    }
}

// ---------------------------------------------------------------------------
extern "C" void kernel_launch(void* const* d_in, const int* in_sizes, int n_in,
                              void* d_out, int out_size, void* d_ws, size_t ws_size,
                              hipStream_t stream)
{
    const float* x    = (const float*)d_in[0];
    const float* bn_g = (const float*)d_in[1];
    const float* bn_b = (const float*)d_in[2];
    const float* cw8  = (const float*)d_in[3];
    const float* w1_8 = (const float*)d_in[4];
    const float* b1_8 = (const float*)d_in[5];
    const float* w2_8 = (const float*)d_in[6];
    const float* b2_8 = (const float*)d_in[7];
    const float* cw4  = (const float*)d_in[8];
    const float* w1_4 = (const float*)d_in[9];
    const float* b1_4 = (const float*)d_in[10];
    const float* w2_4 = (const float*)d_in[11];
    const float* b2_4 = (const float*)d_in[12];
    const float* cw2  = (const float*)d_in[13];
    const float* w1_2 = (const float*)d_in[14];
    const float* b1_2 = (const float*)d_in[15];
    const float* w2_2 = (const float*)d_in[16];
    const float* b2_2 = (const float*)d_in[17];
    const float* gw8  = (const float*)d_in[18];
    const float* gb8  = (const float*)d_in[19];
    const float* al8  = (const float*)d_in[20];
    const float* gw4  = (const float*)d_in[21];
    const float* gb4  = (const float*)d_in[22];
    const float* al4  = (const float*)d_in[23];
    const float* gw2  = (const float*)d_in[24];
    const float* gb2  = (const float*)d_in[25];
    const float* al2  = (const float*)d_in[26];
    const float* gw1  = (const float*)d_in[27];
    const float* gb1  = (const float*)d_in[28];
    const float* al1  = (const float*)d_in[29];

    // workspace (~172 MB)
    float*    p_xn  = (float*)d_ws;                    // TOT
    float*    p_t1  = p_xn + TOT;                      // TOT
    ushort_t* p_H8  = (ushort_t*)(p_t1 + TOT);         // 3 x 2*TOT bf16 (H8|H4|H2)
    ushort_t* p_wb  = p_H8 + 6 * (size_t)TOT;          // 4063232 bf16 weights
    ushort_t* p_w1b = p_wb;                            // w1b8|w1b4|w1b2
    ushort_t* p_w2b = p_wb + 917504;                   // w2b8|w2b4|w2b2
    float*    p_sc  = (float*)(p_wb + 4063232);        // CLn
    float*    p_sh  = p_sc + CLn;                      // CLn
    float*    p_w2cs = p_sh + CLn;                     // 3*1024
    float*    p_rs  = p_w2cs + 3 * 1024;               // 4*BC
    float*    p_g   = p_rs + 4 * BC;                   // 256
    // A-tiles (bf16 down|trend per scale) aliased into d_out season half
    ushort_t* p_A8 = (ushort_t*)d_out;                 // 2*BC*128
    ushort_t* p_A4 = p_A8 + 2 * (size_t)BC * 128;      // 2*BC*256
    ushort_t* p_A2 = p_A4 + 2 * (size_t)BC * 256;      // 2*BC*512
    float*    p_season = (float*)d_out;
    float*    p_trend  = (float*)d_out + TOT;

    bn_stats_kernel<<<CLn / 256, 256, 0, stream>>>(x, bn_g, bn_b, p_sc, p_sh);
    xn_kernel<<<TOT / 256, 256, 0, stream>>>(x, p_sc, p_sh, p_xn);
    ema_kernel<16, float><<<BC, 64, 0, stream>>>(p_xn, al1, p_t1);
    convert_weights_kernel<<<4063232 / 256, 256, 0, stream>>>(
        w1_8, w1_4, w1_2, w2_8, w2_4, w2_2, p_wb);
    w2colsum_kernel<<<dim3(16, 3), 256, 0, stream>>>(w2_8, w2_4, w2_2, p_w2cs);

    dwconv_kernel<8><<<BC * 128 / 256, 256, 0, stream>>>(p_xn, cw8, p_A8);
    dwconv_kernel<4><<<BC * 256 / 256, 256, 0, stream>>>(p_xn, cw4, p_A4);
    dwconv_kernel<2><<<BC * 512 / 256, 256, 0, stream>>>(p_xn, cw2, p_A2);
    ema_kernel<2, ushort_t><<<BC, 64, 0, stream>>>(p_A8, al8, p_A8 + (size_t)BC * 128);
    ema_kernel<4, ushort_t><<<BC, 64, 0, stream>>>(p_A4, al4, p_A4 + (size_t)BC * 256);
    ema_kernel<8, ushort_t><<<BC, 64, 0, stream>>>(p_A2, al2, p_A2 + (size_t)BC * 512);

    // batched GEMM1: H_s = gelu(D_s @ W1_s^T + b1_s)   grid x = M-tile (fast)
    gemm1_kernel<<<dim3(128, 8, 3), 256, 0, stream>>>(
        p_A8, p_w1b, b1_8, b1_4, b1_2, p_H8);

    // gates
    rowsum_h_kernel<<<dim3(BC, 3), 256, 0, stream>>>(p_H8, p_w2cs, p_rs);
    rowdiff_sum_kernel<<<BC, 256, 0, stream>>>(p_xn, p_t1, p_rs + 3 * BC);
    gate_kernel<<<Bdim, 128, 0, stream>>>(p_rs, gw8, gb8, gw4, gb4,
                                          gw2, gb2, gw1, gb1, p_g);

    // fused write-only output GEMMs (K=3072): trend first, then season
    dim3 g2(64, 8);   // x = M-tile (fast), y = N-tile
    gemm2_kernel<0><<<g2, 256, 0, stream>>>(p_H8, p_w2b, b2_8, b2_4, b2_2,
                                            p_g, p_t1, nullptr, p_trend);
    gemm2_kernel<1><<<g2, 256, 0, stream>>>(p_H8, p_w2b, b2_8, b2_4, b2_2,
                                            p_g, p_xn, p_trend, p_season);
}

// Round 6
// 534.318 us; speedup vs baseline: 4.0235x; 1.1956x over previous
//
#include <hip/hip_runtime.h>
#include <hip/hip_bf16.h>
#include <math.h>

// Problem constants
#define Bdim 64
#define Cdim 128
#define Ldim 1024
#define BC   (Bdim * Cdim)      // 8192 rows
#define CLn  (Cdim * Ldim)      // 131072 features
#define TOT  (Bdim * CLn)       // 8388608 elements per (B,C,L) tensor

typedef unsigned short ushort_t;
typedef short s16x8 __attribute__((ext_vector_type(8)));   // 8 bf16 (4 VGPRs)
typedef float f32x4 __attribute__((ext_vector_type(4)));

__device__ __forceinline__ float bf2f(ushort_t u) {
    return __uint_as_float(((unsigned)u) << 16);
}
__device__ __forceinline__ ushort_t f2bf(float f) {
    __hip_bfloat16 h = __float2bfloat16(f);
    return *(ushort_t*)&h;
}
// async global->LDS, 16B per lane; lds base wave-uniform, lane i -> base+i*16B
__device__ __forceinline__ void async16(const ushort_t* g, ushort_t* l) {
    __builtin_amdgcn_global_load_lds(
        (const __attribute__((address_space(1))) unsigned int*)g,
        (__attribute__((address_space(3))) unsigned int*)l, 16, 0, 0);
}
// fast GELU (tanh form): z*sigmoid(1.5957691(z + 0.044715 z^3)); |err|<~3e-4
__device__ __forceinline__ float fast_gelu(float z) {
    float z2 = z * z;
    float inner = fmaf(0.044715f * z2, z, z);
    float e = __expf(-1.5957691216057308f * inner);
    return z * __builtin_amdgcn_rcpf(1.f + e);
}

// ---------------------------------------------------------------------------
// BN: per-feature mean/var over batch axis -> fused scale/shift
// ---------------------------------------------------------------------------
__global__ __launch_bounds__(256) void bn_stats_kernel(
    const float* __restrict__ x, const float* __restrict__ bn_g,
    const float* __restrict__ bn_b, float* __restrict__ scale,
    float* __restrict__ shift)
{
    int f = blockIdx.x * 256 + threadIdx.x;
    float sum = 0.f, sumsq = 0.f;
    for (int b = 0; b < Bdim; ++b) {
        float v = x[(size_t)b * CLn + f];
        sum += v; sumsq += v * v;
    }
    float mu  = sum * (1.f / Bdim);
    float var = fmaxf(sumsq * (1.f / Bdim) - mu * mu, 0.f);
    float sc  = bn_g[f] / sqrtf(var + 1e-5f);
    scale[f] = sc;
    shift[f] = bn_b[f] - mu * sc;
}

// ---------------------------------------------------------------------------
// fp32 -> bf16 weight conversion (all 6 weight matrices, one launch)
// ---------------------------------------------------------------------------
__global__ __launch_bounds__(256) void convert_weights_kernel(
    const float* __restrict__ w1_8, const float* __restrict__ w1_4,
    const float* __restrict__ w1_2, const float* __restrict__ w2_8,
    const float* __restrict__ w2_4, const float* __restrict__ w2_2,
    ushort_t* __restrict__ dst)
{
    int idx = blockIdx.x * 256 + threadIdx.x;   // < 4063232 exact
    const float* src; int off;
    if      (idx < 131072)  { src = w1_8; off = 0; }
    else if (idx < 393216)  { src = w1_4; off = 131072; }
    else if (idx < 917504)  { src = w1_2; off = 393216; }
    else if (idx < 1966080) { src = w2_8; off = 917504; }
    else if (idx < 3014656) { src = w2_4; off = 1966080; }
    else                    { src = w2_2; off = 3014656; }
    dst[idx] = f2bf(src[idx - off]);
}

// ---------------------------------------------------------------------------
// column sums of the three W2 matrices (gate matvec trick), 4-way l-split
// ---------------------------------------------------------------------------
__global__ __launch_bounds__(256) void w2colsum_kernel(
    const float* __restrict__ w2_8, const float* __restrict__ w2_4,
    const float* __restrict__ w2_2, float* __restrict__ w2cs)
{
    const float* w = (blockIdx.y == 0) ? w2_8 : (blockIdx.y == 1) ? w2_4 : w2_2;
    int h  = blockIdx.x * 64 + (threadIdx.x & 63);
    int ls = threadIdx.x >> 6;
    float s = 0.f;
    for (int l = ls; l < 1024; l += 4) s += w[(size_t)l * 1024 + h];
    __shared__ float red[4][64];
    red[ls][threadIdx.x & 63] = s;
    __syncthreads();
    if (ls == 0)
        w2cs[blockIdx.y * 1024 + h] =
            red[0][threadIdx.x] + red[1][threadIdx.x] +
            red[2][threadIdx.x] + red[3][threadIdx.x];
}

// ---------------------------------------------------------------------------
// EMA wave routine (reference fp32-underflow semantics; see round-0 notes).
// One 64-lane wave scans Ls = SEG*64 elements from LDS, writes bf16 trend,
// returns lane-local sum of (src - trend) for the rowdiff (wave0 only).
// ---------------------------------------------------------------------------
template<int SEG>
__device__ float ema_wave(const float* __restrict__ src, float a,
                          ushort_t* __restrict__ dst)
{
    const int Ls = SEG * 64;
    int lane = threadIdx.x & 63;
    float m = 1.f - a;
    float xs[SEG];
#pragma unroll
    for (int i = 0; i < SEG; ++i) xs[i] = src[lane * SEG + i];

    float p = 0.f;
#pragma unroll
    for (int i = 0; i < SEG; ++i) {
        float bi = a * xs[i];
        if (lane == 0 && i == 0) bi = xs[0];   // w_num[0] has coefficient 1
        p = fmaf(m, p, bi);
    }
    float Sm = powf(m, (float)SEG);
    float Sp = p;
#pragma unroll
    for (int d = 1; d < 64; d <<= 1) {
        float pm = __shfl_up(Sp, d);
        float mm = __shfl_up(Sm, d);
        if (lane >= d) { Sp = fmaf(Sm, pm, Sp); Sm = Sm * mm; }
    }
    float carry = __shfl_up(Sp, 1);
    if (lane == 0) carry = 0.f;

    double log2m = log2((double)m);
    float y  = carry;
    float mp = powf(m, (float)(lane * SEG + 1));
    float diff = 0.f;
#pragma unroll
    for (int i = 0; i < SEG; ++i) {
        int t = lane * SEG + i;
        float bi = a * xs[i];
        if (lane == 0 && i == 0) bi = xs[0];
        y = fmaf(m, y, bi);
        float dt = (1.f - mp) / a;
        mp *= m;
        double arg = (double)(Ls - 1 - t) * log2m + log2((double)dt)
                     + 39.863137138648355;   // -log2(1e-12)
        float ramp = (arg >= 0.0) ? 1.f : exp2f((float)arg);
        float tr = (y / dt) * ramp;
        dst[t] = f2bf(tr);
        diff += xs[i] - tr;
    }
    return diff;
}

// ---------------------------------------------------------------------------
// MEGA preprocessing kernel: one block per row r = b*C + c.
//  1) xn = x*scale + shift  (LDS fp32 + bf16 global)
//  2) depthwise conv s=2,4,8 from LDS -> bf16 "down" halves + LDS fp32
//  3) 4 EMA scans, one per wave: t1 (from xn) and trend halves for s=2,4,8
//  4) wave0 writes rs[3*BC + r] = sum(xn - t1)
// ---------------------------------------------------------------------------
__global__ __launch_bounds__(256) void pre_kernel(
    const float* __restrict__ x, const float* __restrict__ scale,
    const float* __restrict__ shift,
    const float* __restrict__ cw8, const float* __restrict__ cw4,
    const float* __restrict__ cw2,
    const float* __restrict__ al8, const float* __restrict__ al4,
    const float* __restrict__ al2, const float* __restrict__ al1,
    ushort_t* __restrict__ xn_bf, ushort_t* __restrict__ t1_bf,
    ushort_t* __restrict__ A8, ushort_t* __restrict__ A4,
    ushort_t* __restrict__ A2, float* __restrict__ rs)
{
    __shared__ float sxn[1024];
    __shared__ float sconv[896];   // conv2 [0,512) | conv4 [512,768) | conv8 [768,896)
    int r   = blockIdx.x;          // row = b*C + c
    int c   = r & (Cdim - 1);
    int tid = threadIdx.x;

    // 1) xn
    {
        const float* xr = x + (size_t)r * 1024;
        float4 xv = *(const float4*)(xr + tid * 4);
        float4 sc = *(const float4*)(scale + (size_t)c * 1024 + tid * 4);
        float4 sh = *(const float4*)(shift + (size_t)c * 1024 + tid * 4);
        float v0 = fmaf(xv.x, sc.x, sh.x);
        float v1 = fmaf(xv.y, sc.y, sh.y);
        float v2 = fmaf(xv.z, sc.z, sh.z);
        float v3 = fmaf(xv.w, sc.w, sh.w);
        sxn[tid * 4 + 0] = v0; sxn[tid * 4 + 1] = v1;
        sxn[tid * 4 + 2] = v2; sxn[tid * 4 + 3] = v3;
        uint2 pk;
        pk.x = (unsigned)f2bf(v0) | ((unsigned)f2bf(v1) << 16);
        pk.y = (unsigned)f2bf(v2) | ((unsigned)f2bf(v3) << 16);
        *(uint2*)(xn_bf + (size_t)r * 1024 + tid * 4) = pk;
    }
    __syncthreads();

    // 2) depthwise convs (zero-pad outside [0,1024))
    {
        // conv2: 2 outputs per thread, taps 4
        const float* w2 = cw2 + c * 4;
#pragma unroll
        for (int j = 0; j < 2; ++j) {
            int o = tid * 2 + j;
            int start = o * 2 - 1;
            float acc = 0.f;
#pragma unroll
            for (int k = 0; k < 4; ++k) {
                int pos = start + k;
                float v = (pos >= 0 && pos < 1024) ? sxn[pos] : 0.f;
                acc = fmaf(v, w2[k], acc);
            }
            sconv[o] = acc;
            A2[(size_t)r * 512 + o] = f2bf(acc);
        }
        // conv4: 1 output per thread, taps 8
        {
            const float* w4 = cw4 + c * 8;
            int o = tid;
            int start = o * 4 - 2;
            float acc = 0.f;
#pragma unroll
            for (int k = 0; k < 8; ++k) {
                int pos = start + k;
                float v = (pos >= 0 && pos < 1024) ? sxn[pos] : 0.f;
                acc = fmaf(v, w4[k], acc);
            }
            sconv[512 + o] = acc;
            A4[(size_t)r * 256 + o] = f2bf(acc);
        }
        // conv8: threads < 128, taps 16
        if (tid < 128) {
            const float* w8 = cw8 + c * 16;
            int o = tid;
            int start = o * 8 - 4;
            float acc = 0.f;
#pragma unroll
            for (int k = 0; k < 16; ++k) {
                int pos = start + k;
                float v = (pos >= 0 && pos < 1024) ? sxn[pos] : 0.f;
                acc = fmaf(v, w8[k], acc);
            }
            sconv[768 + o] = acc;
            A8[(size_t)r * 128 + o] = f2bf(acc);
        }
    }
    __syncthreads();

    // 3) EMA scans, one wave each
    int wave = tid >> 6;
    if (wave == 0) {
        float a = (float)(1.0 / (1.0 + exp(-(double)al1[c])));
        float diff = ema_wave<16>(sxn, a, t1_bf + (size_t)r * 1024);
#pragma unroll
        for (int d = 32; d > 0; d >>= 1) diff += __shfl_down(diff, d);
        if ((tid & 63) == 0) rs[3 * BC + r] = diff;
    } else if (wave == 1) {
        float a = (float)(1.0 / (1.0 + exp(-(double)al2[c])));
        ema_wave<8>(sconv, a, A2 + ((size_t)BC + r) * 512);
    } else if (wave == 2) {
        float a = (float)(1.0 / (1.0 + exp(-(double)al4[c])));
        ema_wave<4>(sconv + 512, a, A4 + ((size_t)BC + r) * 256);
    } else {
        float a = (float)(1.0 / (1.0 + exp(-(double)al8[c])));
        ema_wave<2>(sconv + 768, a, A8 + ((size_t)BC + r) * 128);
    }
}

// ---------------------------------------------------------------------------
// GEMM1 batched over 3 scales (blockIdx.z): H_s = bf16(gelu(D_s @ W1_s^T + b1))
// Fused epilogue also accumulates the gate row-sums:
//   rs[z*BC + r] (+)= sign * sum_col gelu(...) * w2cs[z*1024+col]
// grid (128, 8, 3): x = M-tile (fast) for XCD-local A-tile L2 reuse.
// ---------------------------------------------------------------------------
__global__ __launch_bounds__(256) void gemm1_kernel(
    const ushort_t* __restrict__ Abase,   // A8 | A4 | A2 contiguous
    const ushort_t* __restrict__ Wbase,   // w1b8 | w1b4 | w1b2 contiguous
    const float* __restrict__ b1_8, const float* __restrict__ b1_4,
    const float* __restrict__ b1_2, const float* __restrict__ w2cs,
    ushort_t* __restrict__ Hbase, float* __restrict__ rs)
{
    int z = blockIdx.z;
    int K = 128 << z;
    const ushort_t* A  = Abase + (size_t)2 * BC * 128 * ((1 << z) - 1);
    const ushort_t* Bw = Wbase + (size_t)131072 * ((1 << z) - 1);
    const float* bias  = (z == 0) ? b1_8 : (z == 1) ? b1_4 : b1_2;
    ushort_t* Hout     = Hbase + (size_t)z * 2 * TOT;

    __shared__ ushort_t As[128 * 64];
    __shared__ ushort_t Bs[128 * 64];
    int tid  = threadIdx.x;
    int wave = tid >> 6;
    int lane = tid & 63;
    int m0 = blockIdx.x * 128, n0 = blockIdx.y * 128;
    int wm = (wave & 1) * 64, wn = (wave >> 1) * 64;
    int lrow = lane >> 3;
    int pc   = lane & 7;
    int fr   = lane & 15;
    int quad = lane >> 4;

    f32x4 acc[4][4];
#pragma unroll
    for (int i = 0; i < 4; ++i)
#pragma unroll
        for (int j = 0; j < 4; ++j) acc[i][j] = (f32x4){0.f, 0.f, 0.f, 0.f};

    for (int k0 = 0; k0 < K; k0 += 64) {
        __syncthreads();
#pragma unroll
        for (int i = 0; i < 4; ++i) {
            int rb  = wave * 32 + i * 8;
            int row = rb + lrow;
            int lc  = (pc - row) & 7;
            async16(A  + (size_t)(m0 + row) * K + k0 + lc * 8, &As[rb * 64]);
            async16(Bw + (size_t)(n0 + row) * K + k0 + lc * 8, &Bs[rb * 64]);
        }
        __syncthreads();
#pragma unroll
        for (int kk = 0; kk < 64; kk += 32) {
            s16x8 af[4], bfr[4];
            int lcA = (kk >> 3) + quad;
#pragma unroll
            for (int t = 0; t < 4; ++t) {
                int mr  = wm + t * 16 + fr;
                af[t]  = *(const s16x8*)&As[mr * 64 + ((lcA + mr) & 7) * 8];
                int nr  = wn + t * 16 + fr;
                bfr[t] = *(const s16x8*)&Bs[nr * 64 + ((lcA + nr) & 7) * 8];
            }
#pragma unroll
            for (int mt = 0; mt < 4; ++mt)
#pragma unroll
                for (int nt = 0; nt < 4; ++nt)
                    acc[mt][nt] = __builtin_amdgcn_mfma_f32_16x16x32_bf16(
                        af[mt], bfr[nt], acc[mt][nt], 0, 0, 0);
        }
    }
    // epilogue — D layout: m = quad*4 + reg, n = lane&15
    int is_trend = (m0 >= BC);
    float sign = is_trend ? -1.f : 1.f;
    float racc[16];
#pragma unroll
    for (int e = 0; e < 16; ++e) racc[e] = 0.f;
#pragma unroll
    for (int mt = 0; mt < 4; ++mt)
#pragma unroll
        for (int nt = 0; nt < 4; ++nt) {
            int col = n0 + wn + nt * 16 + fr;
            float wcs = w2cs[z * 1024 + col];
#pragma unroll
            for (int rr = 0; rr < 4; ++rr) {
                size_t row = m0 + wm + mt * 16 + quad * 4 + rr;
                float zv = acc[mt][nt][rr] + bias[col];
                float zg = fast_gelu(zv);
                Hout[row * 1024 + col] = f2bf(zg);
                racc[mt * 4 + rr] = fmaf(zg, wcs, racc[mt * 4 + rr]);
            }
        }
    // reduce row partials over the 16 fr lanes, one atomic per row
#pragma unroll
    for (int e = 0; e < 16; ++e) {
        float v = racc[e];
        v += __shfl_xor(v, 1); v += __shfl_xor(v, 2);
        v += __shfl_xor(v, 4); v += __shfl_xor(v, 8);
        if (fr == 0) {
            int mt = e >> 2, rr = e & 3;
            int row = m0 + wm + mt * 16 + quad * 4 + rr;
            int ra  = row - (is_trend ? BC : 0);
            atomicAdd(&rs[z * BC + ra], sign * v);
        }
    }
}

// ---------------------------------------------------------------------------
// GEMM2 (K=3072 scale-concat, single-accumulator gate fold via ratio rescale):
//   sum_s g_s A_sB_s = g2*(A2B2 + (g1/g2)*(A1B1 + (g0/g1)*A0B0))
//   IS_U=0: trend[idx]  = acc + cb2[col] + g1*t1[idx]
//   IS_U=1: season[idx] = acc + cb2[col] + g1*xn[idx] - trend[idx]
// grid (64, 8): x = M-tile (fast) for XCD-local A-tile L2 reuse.
// ---------------------------------------------------------------------------
template<int IS_U>
__global__ __launch_bounds__(256) void gemm2_kernel(
    const ushort_t* __restrict__ Hbase,   // H8 | H4 | H2, each [up|trend] 2*TOT
    const ushort_t* __restrict__ W2base,  // w2b8 | w2b4 | w2b2 contiguous
    const float* __restrict__ b2_8, const float* __restrict__ b2_4,
    const float* __restrict__ b2_2, const float* __restrict__ g,
    const ushort_t* __restrict__ aux,     // bf16 t1 (IS_U=0) or xn (IS_U=1)
    const float* __restrict__ trend_in,   // IS_U=1 only
    float* __restrict__ outp)             // trend half or season half
{
    __shared__ ushort_t As[128 * 64];
    __shared__ ushort_t Bs[128 * 64];
    int tid  = threadIdx.x;
    int wave = tid >> 6;
    int lane = tid & 63;
    int m0 = blockIdx.x * 128, n0 = blockIdx.y * 128;   // M = 8192 rows
    int wm = (wave & 1) * 64, wn = (wave >> 1) * 64;
    int lrow = lane >> 3;
    int pc   = lane & 7;
    int fr   = lane & 15;
    int quad = lane >> 4;
    int b = m0 >> 7;                       // 128 rows = one batch
    float gv0 = g[b * 4 + 0], gv1 = g[b * 4 + 1], gv2 = g[b * 4 + 2];
    float g1  = g[b * 4 + 3];
    float gsv[3] = {gv0, gv1, gv2};

    f32x4 acc[4][4];
#pragma unroll
    for (int i = 0; i < 4; ++i)
#pragma unroll
        for (int j = 0; j < 4; ++j) acc[i][j] = (f32x4){0.f, 0.f, 0.f, 0.f};

    for (int s = 0; s < 3; ++s) {
        if (s > 0) {
            float rr_ = gsv[s - 1] / fmaxf(gsv[s], 1e-30f);
#pragma unroll
            for (int mt = 0; mt < 4; ++mt)
#pragma unroll
                for (int nt = 0; nt < 4; ++nt)
#pragma unroll
                    for (int rr = 0; rr < 4; ++rr)
                        acc[mt][nt][rr] *= rr_;
        }
        const ushort_t* A  = Hbase + (size_t)s * 2 * TOT + (IS_U ? 0 : TOT);
        const ushort_t* Bw = W2base + (size_t)s * 1048576;
        for (int k0 = 0; k0 < 1024; k0 += 64) {
            __syncthreads();
#pragma unroll
            for (int i = 0; i < 4; ++i) {
                int rb  = wave * 32 + i * 8;
                int row = rb + lrow;
                int lc  = (pc - row) & 7;
                async16(A  + (size_t)(m0 + row) * 1024 + k0 + lc * 8, &As[rb * 64]);
                async16(Bw + (size_t)(n0 + row) * 1024 + k0 + lc * 8, &Bs[rb * 64]);
            }
            __syncthreads();
#pragma unroll
            for (int kk = 0; kk < 64; kk += 32) {
                s16x8 af[4], bfr[4];
                int lcA = (kk >> 3) + quad;
#pragma unroll
                for (int t = 0; t < 4; ++t) {
                    int mr  = wm + t * 16 + fr;
                    af[t]  = *(const s16x8*)&As[mr * 64 + ((lcA + mr) & 7) * 8];
                    int nr  = wn + t * 16 + fr;
                    bfr[t] = *(const s16x8*)&Bs[nr * 64 + ((lcA + nr) & 7) * 8];
                }
#pragma unroll
                for (int mt = 0; mt < 4; ++mt)
#pragma unroll
                    for (int nt = 0; nt < 4; ++nt)
                        acc[mt][nt] = __builtin_amdgcn_mfma_f32_16x16x32_bf16(
                            af[mt], bfr[nt], acc[mt][nt], 0, 0, 0);
            }
        }
    }
#pragma unroll
    for (int mt = 0; mt < 4; ++mt)
#pragma unroll
        for (int nt = 0; nt < 4; ++nt)
#pragma unroll
            for (int rr = 0; rr < 4; ++rr)
                acc[mt][nt][rr] *= gv2;

    // epilogue — D layout: m = quad*4 + reg, n = lane&15
#pragma unroll
    for (int mt = 0; mt < 4; ++mt)
#pragma unroll
        for (int nt = 0; nt < 4; ++nt) {
            int col = n0 + wn + nt * 16 + fr;
            float cb2 = gv0 * b2_8[col] + gv1 * b2_4[col] + gv2 * b2_2[col];
#pragma unroll
            for (int r = 0; r < 4; ++r) {
                size_t row = m0 + wm + mt * 16 + quad * 4 + r;
                size_t idx = row * 1024 + col;
                float v = acc[mt][nt][r] + cb2 + g1 * bf2f(aux[idx]);
                if (IS_U) v -= trend_in[idx];   // season
                outp[idx] = v;
            }
        }
}

// ---------------------------------------------------------------------------
// gates: sigmoid(mean_L(season) . gw + gb) per scale, then normalize over 4
// ---------------------------------------------------------------------------
__global__ __launch_bounds__(128) void gate_kernel(
    const float* __restrict__ rs,
    const float* __restrict__ gw8, const float* __restrict__ gb8,
    const float* __restrict__ gw4, const float* __restrict__ gb4,
    const float* __restrict__ gw2, const float* __restrict__ gb2,
    const float* __restrict__ gw1, const float* __restrict__ gb1,
    float* __restrict__ g)
{
    int b = blockIdx.x;
    int c = threadIdx.x;
    const float* gws[4] = {gw8, gw4, gw2, gw1};
    const float* gbs[4] = {gb8, gb4, gb2, gb1};
    __shared__ float buf[128];
    __shared__ float gates[4];
    for (int si = 0; si < 4; ++si) {
        buf[c] = rs[si * BC + b * Cdim + c] * (1.f / Ldim) * gws[si][c];
        __syncthreads();
        for (int off = 64; off >= 1; off >>= 1) {
            if (c < off) buf[c] += buf[c + off];
            __syncthreads();
        }
        if (c == 0) {
            float z = buf[0] + gbs[si][0];
            gates[si] = 1.f / (1.f + expf(-z));
        }
        __syncthreads();
    }
    if (c == 0) {
        float s = gates[0] + gates[1] + gates[2] + gates[3] + 1e-6f;
#pragma unroll
        for (int si = 0; si < 4; ++si) g[b * 4 + si] = gates[si] / s;
    }
}

// ---------------------------------------------------------------------------
extern "C" void kernel_launch(void* const* d_in, const int* in_sizes, int n_in,
                              void* d_out, int out_size, void* d_ws, size_t ws_size,
                              hipStream_t stream)
{
    const float* x    = (const float*)d_in[0];
    const float* bn_g = (const float*)d_in[1];
    const float* bn_b = (const float*)d_in[2];
    const float* cw8  = (const float*)d_in[3];
    const float* w1_8 = (const float*)d_in[4];
    const float* b1_8 = (const float*)d_in[5];
    const float* w2_8 = (const float*)d_in[6];
    const float* b2_8 = (const float*)d_in[7];
    const float* cw4  = (const float*)d_in[8];
    const float* w1_4 = (const float*)d_in[9];
    const float* b1_4 = (const float*)d_in[10];
    const float* w2_4 = (const float*)d_in[11];
    const float* b2_4 = (const float*)d_in[12];
    const float* cw2  = (const float*)d_in[13];
    const float* w1_2 = (const float*)d_in[14];
    const float* b1_2 = (const float*)d_in[15];
    const float* w2_2 = (const float*)d_in[16];
    const float* b2_2 = (const float*)d_in[17];
    const float* gw8  = (const float*)d_in[18];
    const float* gb8  = (const float*)d_in[19];
    const float* al8  = (const float*)d_in[20];
    const float* gw4  = (const float*)d_in[21];
    const float* gb4  = (const float*)d_in[22];
    const float* al4  = (const float*)d_in[23];
    const float* gw2  = (const float*)d_in[24];
    const float* gb2  = (const float*)d_in[25];
    const float* al2  = (const float*)d_in[26];
    const float* gw1  = (const float*)d_in[27];
    const float* gb1  = (const float*)d_in[28];
    const float* al1  = (const float*)d_in[29];

    // workspace (~140 MB)
    ushort_t* p_xn  = (ushort_t*)d_ws;                 // TOT bf16
    ushort_t* p_t1  = p_xn + TOT;                      // TOT bf16
    ushort_t* p_H   = p_t1 + TOT;                      // 6*TOT bf16 (H8|H4|H2)
    ushort_t* p_wb  = p_H + 6 * (size_t)TOT;           // 4063232 bf16 weights
    ushort_t* p_w1b = p_wb;                            // w1b8|w1b4|w1b2
    ushort_t* p_w2b = p_wb + 917504;                   // w2b8|w2b4|w2b2
    float*    p_sc  = (float*)(p_wb + 4063232);        // CLn
    float*    p_sh  = p_sc + CLn;                      // CLn
    float*    p_w2cs = p_sh + CLn;                     // 3*1024
    float*    p_rs  = p_w2cs + 3 * 1024;               // 4*BC
    float*    p_g   = p_rs + 4 * BC;                   // 256
    // A-tiles (bf16 down|trend per scale) aliased into d_out season half
    ushort_t* p_A8 = (ushort_t*)d_out;                 // 2*BC*128
    ushort_t* p_A4 = p_A8 + 2 * (size_t)BC * 128;      // 2*BC*256
    ushort_t* p_A2 = p_A4 + 2 * (size_t)BC * 256;      // 2*BC*512
    float*    p_season = (float*)d_out;
    float*    p_trend  = (float*)d_out + TOT;

    hipMemsetAsync(p_rs, 0, 4 * BC * sizeof(float), stream);
    bn_stats_kernel<<<CLn / 256, 256, 0, stream>>>(x, bn_g, bn_b, p_sc, p_sh);
    convert_weights_kernel<<<4063232 / 256, 256, 0, stream>>>(
        w1_8, w1_4, w1_2, w2_8, w2_4, w2_2, p_wb);
    w2colsum_kernel<<<dim3(16, 3), 256, 0, stream>>>(w2_8, w2_4, w2_2, p_w2cs);

    // fused xn + conv x3 + EMA x4 + scale-1 rowdiff
    pre_kernel<<<BC, 256, 0, stream>>>(x, p_sc, p_sh, cw8, cw4, cw2,
                                       al8, al4, al2, al1,
                                       p_xn, p_t1, p_A8, p_A4, p_A2, p_rs);

    // batched GEMM1 with fused gate row-sums
    gemm1_kernel<<<dim3(128, 8, 3), 256, 0, stream>>>(
        p_A8, p_w1b, b1_8, b1_4, b1_2, p_w2cs, p_H, p_rs);

    gate_kernel<<<Bdim, 128, 0, stream>>>(p_rs, gw8, gb8, gw4, gb4,
                                          gw2, gb2, gw1, gb1, p_g);

    // fused write-only output GEMMs (K=3072): trend first, then season
    dim3 g2(64, 8);   // x = M-tile (fast), y = N-tile
    gemm2_kernel<0><<<g2, 256, 0, stream>>>(p_H, p_w2b, b2_8, b2_4, b2_2,
                                            p_g, p_t1, nullptr, p_trend);
    gemm2_kernel<1><<<g2, 256, 0, stream>>>(p_H, p_w2b, b2_8, b2_4, b2_2,
                                            p_g, p_xn, p_trend, p_season);
}